// Round 3
// baseline (5447.149 us; speedup 1.0000x reference)
//
#include <hip/hip_runtime.h>
#include <hip/hip_bf16.h>
#include <math.h>

typedef __hip_bfloat16 bf16;

// Problem constants
#define Bb 8
#define Nn 256
#define Cc 128
#define Hh 8
#define DEPTHd 4
#define BN 2048           // B*N
#define RTOT 524288       // B*N*N

__device__ inline float toF(float v) { return v; }
__device__ inline float toF(bf16 v) { return __bfloat162float(v); }
__device__ inline void stF(float* p, float v) { *p = v; }
__device__ inline void stF(bf16* p, float v) { *p = __float2bfloat16(v); }

// ---- block reductions (blockDim.x = 128 or 256). sred >= 8 floats. ----
__device__ inline float blk_sum(float v, float* sred) {
#pragma unroll
  for (int off = 32; off; off >>= 1) v += __shfl_down(v, off, 64);
  int wid = threadIdx.x >> 6;
  int lane = threadIdx.x & 63;
  int nw = blockDim.x >> 6;
  if (lane == 0) sred[wid] = v;
  __syncthreads();
  float s = ((int)threadIdx.x < nw) ? sred[threadIdx.x] : 0.f;
  s += __shfl_down(s, 2, 64);
  s += __shfl_down(s, 1, 64);
  if (threadIdx.x == 0) sred[4] = s;
  __syncthreads();
  float r = sred[4];
  __syncthreads();
  return r;
}

__device__ inline float blk_max(float v, float* sred) {
#pragma unroll
  for (int off = 32; off; off >>= 1) v = fmaxf(v, __shfl_down(v, off, 64));
  int wid = threadIdx.x >> 6;
  int lane = threadIdx.x & 63;
  int nw = blockDim.x >> 6;
  if (lane == 0) sred[wid] = v;
  __syncthreads();
  float s = ((int)threadIdx.x < nw) ? sred[threadIdx.x] : -INFINITY;
  s = fmaxf(s, __shfl_down(s, 2, 64));
  s = fmaxf(s, __shfl_down(s, 1, 64));
  if (threadIdx.x == 0) sred[4] = s;
  __syncthreads();
  float r = sred[4];
  __syncthreads();
  return r;
}

// ---- generic linear: out[r][c] = act(in[r][:] @ W[:, c] + bias[c]) (+ resid) ----
// block = 256 threads (one column each), 8 rows per block staged in LDS.
// Requires K <= 512, rows % 8 == 0. Weights/bias are f32 (reference dtype).
template <typename TIN, typename TOUT, bool GELU>
__global__ void k_linear(const TIN* __restrict__ in, const float* __restrict__ W,
                         const float* __restrict__ bias, TOUT* __restrict__ out,
                         const float* __restrict__ resid, int rows, int K, int cols) {
  __shared__ float sin_[8 * 512];
  int t = threadIdx.x;
  int row0 = blockIdx.y * 8;
  int RK = 8 * K;
  for (int idx = t; idx < RK; idx += 256) {
    int r = idx / K;
    int k = idx - r * K;
    int row = row0 + r;
    sin_[idx] = (row < rows) ? toF(in[(long)row * K + k]) : 0.f;
  }
  __syncthreads();
  int c = blockIdx.x * 256 + t;
  if (c >= cols) return;
  float acc[8] = {0.f, 0.f, 0.f, 0.f, 0.f, 0.f, 0.f, 0.f};
  const float* wp = W + c;
#pragma unroll 4
  for (int k = 0; k < K; ++k) {
    float wv = wp[(long)k * cols];
#pragma unroll
    for (int r = 0; r < 8; ++r) acc[r] += sin_[r * K + k] * wv;
  }
  float bv = bias[c];
#pragma unroll
  for (int r = 0; r < 8; ++r) {
    int row = row0 + r;
    if (row < rows) {
      float v = acc[r] + bv;
      if (GELU) v = 0.5f * v * (1.f + erff(v * 0.70710678118654752f));
      if (resid) v += resid[(long)row * cols + c];
      stF(&out[(long)row * cols + c], v);
    }
  }
}

// ---- LayerNorm over last dim 128 ----
__global__ void k_ln(const float* __restrict__ in, const float* __restrict__ g,
                     const float* __restrict__ b, float* __restrict__ out) {
  __shared__ float sred[8];
  int row = blockIdx.x;
  int t = threadIdx.x;
  float x = in[(long)row * 128 + t];
  float mean = blk_sum(x, sred) * (1.f / 128.f);
  float d = x - mean;
  float var = blk_sum(d * d, sred) * (1.f / 128.f);
  out[(long)row * 128 + t] = d * rsqrtf(var + 1e-5f) * g[t] + b[t];
}

// ---- relation epilogue: rf row -> LN2 (all 4 depths) -> rconv -> attn_R (bf16) ----
// grid = chunk rows, block = 128. attnR layout: [d][b][h][n][m]
__global__ void k_attnR(const float* __restrict__ rf, const float* __restrict__ g,
                        const float* __restrict__ bta, const float* __restrict__ W,
                        const float* __restrict__ wb, bf16* __restrict__ attnR,
                        long row0) {
  __shared__ float xs[128];
  __shared__ float sred[8];
  int t = threadIdx.x;
  long lrow = blockIdx.x;
  float x = rf[lrow * 128 + t];
  float mean = blk_sum(x, sred) * (1.f / 128.f);
  float d0 = x - mean;
  float var = blk_sum(d0 * d0, sred) * (1.f / 128.f);
  xs[t] = d0 * rsqrtf(var + 1e-5f);
  __syncthreads();
  if (t < 32) {
    int dd = t >> 3;
    int h = t & 7;
    float acc = wb[dd * 8 + h];
    for (int c = 0; c < 128; ++c) {
      float y = xs[c] * g[dd * 128 + c] + bta[dd * 128 + c];
      acc += y * W[((long)dd * 128 + c) * 8 + h];
    }
    long rr = row0 + lrow;
    int bb = (int)(rr >> 16);
    int n = (int)((rr >> 8) & 255);
    int m = (int)(rr & 255);
    attnR[((((long)dd * Bb + bb) * Hh + h) * Nn + n) * Nn + m] = __float2bfloat16(acc);
  }
}

// ---- fused attention for one depth: logits + conn + softmax + AV ----
// grid = (N, H, B), block = 256 (one m per thread)
__global__ void k_attn(const float* __restrict__ qkv, const bf16* __restrict__ aR,
                       const float* __restrict__ conn, float* __restrict__ obuf) {
  __shared__ float q[16];
  __shared__ float p[256];
  __shared__ float sred[8];
  int n = blockIdx.x, h = blockIdx.y, b = blockIdx.z;
  int t = threadIdx.x;
  if (t < 16) q[t] = qkv[((long)(b * Nn + n)) * 384 + h * 16 + t];
  __syncthreads();
  const float* kp = &qkv[((long)(b * Nn + t)) * 384 + 128 + h * 16];
  float lg = 0.f;
#pragma unroll
  for (int e = 0; e < 16; ++e) lg += q[e] * kp[e];
  lg += toF(aR[(((long)(b * Hh + h) * Nn + n)) * Nn + t]);
  lg = lg * conn[((long)(b * Nn + n)) * Nn + t] * 0.25f;
  float mx = blk_max(lg, sred);
  float ex = expf(lg - mx);
  float s = blk_sum(ex, sred);
  p[t] = ex / s;
  __syncthreads();
  if (t < 16) {
    float acc = 0.f;
    const float* vp = &qkv[((long)(b * Nn)) * 384 + 256 + h * 16 + t];
    for (int m = 0; m < 256; ++m) acc += p[m] * vp[(long)m * 384];
    obuf[((long)(b * Nn + n)) * 128 + h * 16 + t] = acc;
  }
}

extern "C" void kernel_launch(void* const* d_in, const int* in_sizes, int n_in,
                              void* d_out, int out_size, void* d_ws, size_t ws_size,
                              hipStream_t stream) {
  // All reference dtypes are float32 -> cast everything as float.
  const float* joint_in = (const float*)d_in[0];
  const float* relation_in = (const float*)d_in[1];
  const float* conn = (const float*)d_in[2];
  const float* je_w1 = (const float*)d_in[3];
  const float* je_b1 = (const float*)d_in[4];
  const float* je_w2 = (const float*)d_in[5];
  const float* je_b2 = (const float*)d_in[6];
  const float* je_w3 = (const float*)d_in[7];
  const float* je_b3 = (const float*)d_in[8];
  const float* re_w1 = (const float*)d_in[9];
  const float* re_b1 = (const float*)d_in[10];
  const float* re_w2 = (const float*)d_in[11];
  const float* re_b2 = (const float*)d_in[12];
  const float* re_w3 = (const float*)d_in[13];
  const float* re_b3 = (const float*)d_in[14];
  const float* qkv_w = (const float*)d_in[15];
  const float* qkv_b = (const float*)d_in[16];
  const float* rconv_w = (const float*)d_in[17];
  const float* rconv_b = (const float*)d_in[18];
  const float* proj_w = (const float*)d_in[19];
  const float* proj_b = (const float*)d_in[20];
  const float* ln1_g = (const float*)d_in[21];
  const float* ln1_b = (const float*)d_in[22];
  const float* ln2_g = (const float*)d_in[23];
  const float* ln2_b = (const float*)d_in[24];
  const float* ln3_g = (const float*)d_in[25];
  const float* ln3_b = (const float*)d_in[26];
  const float* mw1 = (const float*)d_in[27];
  const float* mb1 = (const float*)d_in[28];
  const float* mw2 = (const float*)d_in[29];
  const float* mb2 = (const float*)d_in[30];
  const float* ng = (const float*)d_in[31];
  const float* nb = (const float*)d_in[32];
  const float* dw1 = (const float*)d_in[33];
  const float* db1 = (const float*)d_in[34];
  const float* dw2 = (const float*)d_in[35];
  const float* db2 = (const float*)d_in[36];
  const float* dw3 = (const float*)d_in[37];
  const float* db3 = (const float*)d_in[38];

  // ---- ws-size-adaptive carve-up ----
  char* ws = (char*)d_ws;
  size_t off = 0;
  auto alloc = [&](size_t bytes) -> void* {
    void* p = ws + off;
    off += (bytes + 255) & ~(size_t)255;
    return p;
  };
  // persistent buffers (~41 MB)
  bf16* attnR = (bf16*)alloc((size_t)DEPTHd * Bb * Hh * Nn * Nn * 2);  // 33.55 MB
  float* jf = (float*)alloc((size_t)BN * 128 * 4);
  float* xb = (float*)alloc((size_t)BN * 128 * 4);
  float* qkvb = (float*)alloc((size_t)BN * 384 * 4);
  float* obuf = (float*)alloc((size_t)BN * 128 * 4);
  float* hbuf = (float*)alloc((size_t)BN * 128 * 4);
  // arena: shared by (joint-enc scratch) -> (relation chunk bufs) -> (decoder scratch)
  char* arena = ws + off;
  size_t avail = (ws_size > off) ? (ws_size - off) : 0;
  // relation chunk rows: CH*1536 bytes of arena. Deterministic in ws_size.
  int CH = 2048;
  for (int c = 65536; c >= 2048; c >>= 1) {
    if ((size_t)c * 1536 <= avail) { CH = c; break; }
  }
  bf16* bufA = (bf16*)arena;                             // CH*256 bf16
  bf16* bufB = (bf16*)(arena + (size_t)CH * 512);        // CH*256 bf16
  float* bufC = (float*)(arena + (size_t)CH * 1024);     // CH*128 f32
  float* d1 = (float*)arena;                             // BN*256 f32 (2.1 MB)
  float* d2 = (float*)(arena + (size_t)BN * 256 * 4);    // BN*512 f32 (4.2 MB)

#define LIN(TIN, TOUT, GELU, inp, Wp, bp, outp, residp, rows, K, cols)                  \
  k_linear<TIN, TOUT, GELU><<<dim3(((cols) + 255) / 256, (rows) / 8), dim3(256), 0,     \
                              stream>>>(inp, Wp, bp, outp, residp, rows, K, cols)

  // ---- joint encoder: 96 -> 256 -> 256 -> 128 (arena as d1/d2) ----
  LIN(float, float, false, joint_in, je_w1, je_b1, d1, (const float*)nullptr, BN, 96, 256);
  LIN(float, float, false, d1, je_w2, je_b2, d2, (const float*)nullptr, BN, 256, 256);
  LIN(float, float, false, d2, je_w3, je_b3, jf, (const float*)nullptr, BN, 256, 128);

  // ---- relation encoder, chunked, fused LN2+rconv epilogue -> attn_R ----
  int nchunk = RTOT / CH;
  for (int ci = 0; ci < nchunk; ++ci) {
    long row0 = (long)ci * CH;
    LIN(float, bf16, false, relation_in + row0 * 26, re_w1, re_b1, bufA,
        (const float*)nullptr, CH, 26, 256);
    LIN(bf16, bf16, false, bufA, re_w2, re_b2, bufB, (const float*)nullptr, CH, 256, 256);
    LIN(bf16, float, false, bufB, re_w3, re_b3, bufC, (const float*)nullptr, CH, 256, 128);
    k_attnR<<<dim3(CH), dim3(128), 0, stream>>>(bufC, ln2_g, ln2_b, rconv_w,
                                                rconv_b, attnR, row0);
  }

  // ---- transformer blocks ----
  for (int d = 0; d < DEPTHd; ++d) {
    k_ln<<<dim3(BN), dim3(128), 0, stream>>>(jf, ln1_g + d * 128, ln1_b + d * 128, xb);
    LIN(float, float, false, xb, qkv_w + (size_t)d * 128 * 384, qkv_b + d * 384, qkvb,
        (const float*)nullptr, BN, 128, 384);
    k_attn<<<dim3(Nn, Hh, Bb), dim3(256), 0, stream>>>(
        qkvb, attnR + (size_t)d * Bb * Hh * Nn * Nn, conn, obuf);
    LIN(float, float, false, obuf, proj_w + (size_t)d * 128 * 128, proj_b + d * 128, jf,
        (const float*)jf, BN, 128, 128);
    k_ln<<<dim3(BN), dim3(128), 0, stream>>>(jf, ln3_g + d * 128, ln3_b + d * 128, xb);
    LIN(float, float, true, xb, mw1 + (size_t)d * 128 * 128, mb1 + d * 128, hbuf,
        (const float*)nullptr, BN, 128, 128);
    LIN(float, float, false, hbuf, mw2 + (size_t)d * 128 * 128, mb2 + d * 128, jf,
        (const float*)jf, BN, 128, 128);
  }

  // ---- final LN + decoder 128 -> 256 -> 512 -> 90 (arena as d1/d2) ----
  k_ln<<<dim3(BN), dim3(128), 0, stream>>>(jf, ng, nb, xb);
  LIN(float, float, false, xb, dw1, db1, d1, (const float*)nullptr, BN, 128, 256);
  LIN(float, float, false, d1, dw2, db2, d2, (const float*)nullptr, BN, 256, 512);
  LIN(float, float, false, d2, dw3, db3, (float*)d_out, (const float*)nullptr, BN, 512, 90);

#undef LIN
}

// Round 4
// 1534.855 us; speedup vs baseline: 3.5490x; 3.5490x over previous
//
#include <hip/hip_runtime.h>
#include <hip/hip_bf16.h>
#include <math.h>

typedef __hip_bfloat16 bf16;
typedef __attribute__((ext_vector_type(8))) short short8;
typedef __attribute__((ext_vector_type(4))) float f32x4;

// Problem constants
#define Bb 8
#define Nn 256
#define Cc 128
#define Hh 8
#define DEPTHd 4
#define BN 2048           // B*N
#define RTOT 524288       // B*N*N

__device__ inline float toF(float v) { return v; }
__device__ inline float toF(bf16 v) { return __bfloat162float(v); }
__device__ inline void stF(float* p, float v) { *p = v; }
__device__ inline void stF(bf16* p, float v) { *p = __float2bfloat16(v); }

// ---- block reductions (blockDim.x = 128 or 256). sred >= 8 floats. ----
__device__ inline float blk_sum(float v, float* sred) {
#pragma unroll
  for (int off = 32; off; off >>= 1) v += __shfl_down(v, off, 64);
  int wid = threadIdx.x >> 6;
  int lane = threadIdx.x & 63;
  int nw = blockDim.x >> 6;
  if (lane == 0) sred[wid] = v;
  __syncthreads();
  float s = ((int)threadIdx.x < nw) ? sred[threadIdx.x] : 0.f;
  s += __shfl_down(s, 2, 64);
  s += __shfl_down(s, 1, 64);
  if (threadIdx.x == 0) sred[4] = s;
  __syncthreads();
  float r = sred[4];
  __syncthreads();
  return r;
}

__device__ inline float blk_max(float v, float* sred) {
#pragma unroll
  for (int off = 32; off; off >>= 1) v = fmaxf(v, __shfl_down(v, off, 64));
  int wid = threadIdx.x >> 6;
  int lane = threadIdx.x & 63;
  int nw = blockDim.x >> 6;
  if (lane == 0) sred[wid] = v;
  __syncthreads();
  float s = ((int)threadIdx.x < nw) ? sred[threadIdx.x] : -INFINITY;
  s = fmaxf(s, __shfl_down(s, 2, 64));
  s = fmaxf(s, __shfl_down(s, 1, 64));
  if (threadIdx.x == 0) sred[4] = s;
  __syncthreads();
  float r = sred[4];
  __syncthreads();
  return r;
}

// =============== MFMA GEMM: C[rows][cols] = A[rows][Ka] @ Wt^T + bias ===============
// Wt is pre-transposed bf16 [cols][Kp], Kp = Ka rounded up to 32.
// Tile 128x128 per block (256 thr = 4 waves in 2x2, each wave 64x64 = 4x4 mfma tiles).
// TA=float: generic scalar staging with zero-pad (any Ka). TA=bf16: Ka%32==0, 16B loads.
// STATS (requires cols==128): also emit per-row LayerNorm stats (mean, rsqrt(var+eps)).
template <typename TA, typename TC, bool STATS>
__global__ __launch_bounds__(256) void k_gemm_mfma(
    const TA* __restrict__ A, int Ka, int Kp, const bf16* __restrict__ Bt,
    const float* __restrict__ bias, TC* __restrict__ C, int cols,
    float2* __restrict__ stats) {
  __shared__ __align__(16) bf16 sA[128 * 32];
  __shared__ __align__(16) bf16 sB[128 * 32];
  __shared__ float sstat[128][2][2];

  const int t = threadIdx.x;
  const int lane = t & 63;
  const int wv = t >> 6;
  const int wr = wv >> 1, wc = wv & 1;
  const int lrow = lane & 15, quad = lane >> 4;
  const long row0 = (long)blockIdx.y * 128;
  const int n0 = blockIdx.x * 128;

  f32x4 zero = {0.f, 0.f, 0.f, 0.f};
  f32x4 acc[4][4];
#pragma unroll
  for (int i = 0; i < 4; ++i)
#pragma unroll
    for (int j = 0; j < 4; ++j) acc[i][j] = zero;

  for (int k0 = 0; k0 < Kp; k0 += 32) {
    // ---- stage A tile [128][32] ----
    if (sizeof(TA) == 2) {
      const int r = t >> 2, koff = (t & 3) * 8;
#pragma unroll
      for (int it = 0; it < 2; ++it) {
        int rr = r + it * 64;
        *(uint4*)&sA[rr * 32 + koff] =
            *(const uint4*)&A[(row0 + rr) * (long)Ka + k0 + koff];
      }
    } else {
      for (int idx = t; idx < 128 * 32; idx += 256) {
        int r = idx >> 5, k = idx & 31;
        int gk = k0 + k;
        float v = (gk < Ka) ? toF(A[(row0 + r) * (long)Ka + gk]) : 0.f;
        sA[idx] = __float2bfloat16(v);
      }
    }
    // ---- stage B tile [128][32] (always bf16, Kp%32==0) ----
    {
      const int r = t >> 2, koff = (t & 3) * 8;
#pragma unroll
      for (int it = 0; it < 2; ++it) {
        int rr = r + it * 64;
        *(uint4*)&sB[rr * 32 + koff] =
            *(const uint4*)&Bt[(long)(n0 + rr) * Kp + k0 + koff];
      }
    }
    __syncthreads();
    short8 af[4], bfr[4];
#pragma unroll
    for (int i = 0; i < 4; ++i)
      af[i] = *(const short8*)&sA[(wr * 64 + i * 16 + lrow) * 32 + quad * 8];
#pragma unroll
    for (int j = 0; j < 4; ++j)
      bfr[j] = *(const short8*)&sB[(wc * 64 + j * 16 + lrow) * 32 + quad * 8];
#pragma unroll
    for (int i = 0; i < 4; ++i)
#pragma unroll
      for (int j = 0; j < 4; ++j)
        acc[i][j] =
            __builtin_amdgcn_mfma_f32_16x16x32_bf16(af[i], bfr[j], acc[i][j], 0, 0, 0);
    __syncthreads();
  }

  // ---- epilogue: bias add, store, optional LN stats ----
#pragma unroll
  for (int i = 0; i < 4; ++i) {
#pragma unroll
    for (int r = 0; r < 4; ++r) {
      int rl = wr * 64 + i * 16 + quad * 4 + r;
      long gr = row0 + rl;
      float s1 = 0.f, s2 = 0.f;
#pragma unroll
      for (int j = 0; j < 4; ++j) {
        int gc = n0 + wc * 64 + j * 16 + lrow;
        float v = acc[i][j][r] + bias[gc];
        stF(&C[gr * cols + gc], v);
        if (STATS) { s1 += v; s2 += v * v; }
      }
      if (STATS) {
#pragma unroll
        for (int m = 1; m < 16; m <<= 1) {
          s1 += __shfl_xor(s1, m, 64);
          s2 += __shfl_xor(s2, m, 64);
        }
        if (lrow == 0) {
          sstat[rl][wc][0] = s1;
          sstat[rl][wc][1] = s2;
        }
      }
    }
  }
  if (STATS) {
    __syncthreads();
    if (t < 128) {
      float s1 = sstat[t][0][0] + sstat[t][1][0];
      float s2 = sstat[t][0][1] + sstat[t][1][1];
      float mu = s1 * (1.f / 128.f);
      float var = s2 * (1.f / 128.f) - mu * mu;
      stats[row0 + t] = make_float2(mu, rsqrtf(var + 1e-5f));
    }
  }
}

// =============== small MFMA GEMM: X[rows][128] @ gWt^T -> attnR (scatter) ===============
// Per block: 256 rows x 32 cols. out = inv*(acc - mu*sgW[col]) + bconst[col].
__global__ __launch_bounds__(256) void k_gemm32(
    const bf16* __restrict__ X, const float2* __restrict__ stats,
    const bf16* __restrict__ gWt, const float* __restrict__ sgW,
    const float* __restrict__ bconst, bf16* __restrict__ attnR, long row0g) {
  __shared__ __align__(16) bf16 sA[256 * 32];
  __shared__ __align__(16) bf16 sB[32 * 32];
  __shared__ float sW[64];
  const int t = threadIdx.x;
  const int lane = t & 63, wv = t >> 6;
  const int lrow = lane & 15, quad = lane >> 4;
  const long rb = (long)blockIdx.x * 256;
  if (t < 32) {
    sW[t] = sgW[t];
    sW[32 + t] = bconst[t];
  }
  f32x4 zero = {0.f, 0.f, 0.f, 0.f};
  f32x4 acc[4][2];
#pragma unroll
  for (int i = 0; i < 4; ++i) {
    acc[i][0] = zero;
    acc[i][1] = zero;
  }
  const int koff = (t & 3) * 8;
  for (int k0 = 0; k0 < 128; k0 += 32) {
#pragma unroll
    for (int it = 0; it < 4; ++it) {
      int rr = (t >> 2) + it * 64;
      *(uint4*)&sA[rr * 32 + koff] = *(const uint4*)&X[(rb + rr) * 128 + k0 + koff];
    }
    if (t < 128) {
      int rr = t >> 2;
      *(uint4*)&sB[rr * 32 + koff] = *(const uint4*)&gWt[rr * 128 + k0 + koff];
    }
    __syncthreads();
    short8 af[4], bfr[2];
#pragma unroll
    for (int i = 0; i < 4; ++i)
      af[i] = *(const short8*)&sA[(wv * 64 + i * 16 + lrow) * 32 + quad * 8];
#pragma unroll
    for (int j = 0; j < 2; ++j)
      bfr[j] = *(const short8*)&sB[(j * 16 + lrow) * 32 + quad * 8];
#pragma unroll
    for (int i = 0; i < 4; ++i)
#pragma unroll
      for (int j = 0; j < 2; ++j)
        acc[i][j] =
            __builtin_amdgcn_mfma_f32_16x16x32_bf16(af[i], bfr[j], acc[i][j], 0, 0, 0);
    __syncthreads();
  }
#pragma unroll
  for (int i = 0; i < 4; ++i) {
#pragma unroll
    for (int r = 0; r < 4; ++r) {
      int rl = wv * 64 + i * 16 + quad * 4 + r;
      long grl = rb + rl;
      float2 st = stats[grl];
      long gr = row0g + grl;
      int bb = (int)(gr >> 16);
      int nn = (int)((gr >> 8) & 255);
      int mm = (int)(gr & 255);
#pragma unroll
      for (int j = 0; j < 2; ++j) {
        int col = j * 16 + lrow;
        float v = st.y * (acc[i][j][r] - st.x * sW[col]) + sW[32 + col];
        int dd = col >> 3, h = col & 7;
        attnR[((((long)dd * Bb + bb) * Hh + h) * Nn + nn) * Nn + mm] =
            __float2bfloat16(v);
      }
    }
  }
}

// ---- prep: transpose+cast weights, build gW / sgW / bconst ----
__global__ void k_prep(const float* __restrict__ re_w1, const float* __restrict__ re_w2,
                       const float* __restrict__ re_w3, const float* __restrict__ ln2_g,
                       const float* __restrict__ ln2_b, const float* __restrict__ rconv_w,
                       const float* __restrict__ rconv_b, bf16* __restrict__ Wt1,
                       bf16* __restrict__ Wt2, bf16* __restrict__ Wt3,
                       bf16* __restrict__ gWt, float* __restrict__ sgW,
                       float* __restrict__ bconst) {
  int idx = blockIdx.x * 256 + threadIdx.x;
  if (idx < 65536) {
    int n = idx >> 8, k = idx & 255;
    Wt2[n * 256 + k] = __float2bfloat16(re_w2[k * 256 + n]);
  }
  if (idx < 32768) {
    int n = idx >> 8, k = idx & 255;
    Wt3[n * 256 + k] = __float2bfloat16(re_w3[k * 128 + n]);
  }
  if (idx < 8192) {
    int n = idx >> 5, k = idx & 31;
    Wt1[n * 32 + k] = __float2bfloat16((k < 26) ? re_w1[k * 256 + n] : 0.f);
  }
  if (idx < 4096) {
    int col = idx >> 7, c = idx & 127;
    int dd = col >> 3, h = col & 7;
    gWt[col * 128 + c] =
        __float2bfloat16(ln2_g[dd * 128 + c] * rconv_w[(dd * 128 + c) * 8 + h]);
  }
  if (idx < 32) {
    int dd = idx >> 3, h = idx & 7;
    float sg = 0.f, bc = 0.f;
    for (int c = 0; c < 128; ++c) {
      float w = rconv_w[(dd * 128 + c) * 8 + h];
      sg += ln2_g[dd * 128 + c] * w;
      bc += ln2_b[dd * 128 + c] * w;
    }
    sgW[idx] = sg;
    bconst[idx] = bc + rconv_b[idx];
  }
}

// ---- generic linear (VALU) for the small joint/transformer/decoder GEMMs ----
template <typename TIN, typename TOUT, bool GELU>
__global__ void k_linear(const TIN* __restrict__ in, const float* __restrict__ W,
                         const float* __restrict__ bias, TOUT* __restrict__ out,
                         const float* __restrict__ resid, int rows, int K, int cols) {
  __shared__ float sin_[8 * 512];
  int t = threadIdx.x;
  int row0 = blockIdx.y * 8;
  int RK = 8 * K;
  for (int idx = t; idx < RK; idx += 256) {
    int r = idx / K;
    int k = idx - r * K;
    int row = row0 + r;
    sin_[idx] = (row < rows) ? toF(in[(long)row * K + k]) : 0.f;
  }
  __syncthreads();
  int c = blockIdx.x * 256 + t;
  if (c >= cols) return;
  float acc[8] = {0.f, 0.f, 0.f, 0.f, 0.f, 0.f, 0.f, 0.f};
  const float* wp = W + c;
#pragma unroll 4
  for (int k = 0; k < K; ++k) {
    float wv = wp[(long)k * cols];
#pragma unroll
    for (int r = 0; r < 8; ++r) acc[r] += sin_[r * K + k] * wv;
  }
  float bv = bias[c];
#pragma unroll
  for (int r = 0; r < 8; ++r) {
    int row = row0 + r;
    if (row < rows) {
      float v = acc[r] + bv;
      if (GELU) v = 0.5f * v * (1.f + erff(v * 0.70710678118654752f));
      if (resid) v += resid[(long)row * cols + c];
      stF(&out[(long)row * cols + c], v);
    }
  }
}

// ---- LayerNorm over last dim 128 ----
__global__ void k_ln(const float* __restrict__ in, const float* __restrict__ g,
                     const float* __restrict__ b, float* __restrict__ out) {
  __shared__ float sred[8];
  int row = blockIdx.x;
  int t = threadIdx.x;
  float x = in[(long)row * 128 + t];
  float mean = blk_sum(x, sred) * (1.f / 128.f);
  float d = x - mean;
  float var = blk_sum(d * d, sred) * (1.f / 128.f);
  out[(long)row * 128 + t] = d * rsqrtf(var + 1e-5f) * g[t] + b[t];
}

// ---- fused attention for one depth: logits + conn + softmax + AV ----
__global__ void k_attn(const float* __restrict__ qkv, const bf16* __restrict__ aR,
                       const float* __restrict__ conn, float* __restrict__ obuf) {
  __shared__ float q[16];
  __shared__ float p[256];
  __shared__ float sred[8];
  int n = blockIdx.x, h = blockIdx.y, b = blockIdx.z;
  int t = threadIdx.x;
  if (t < 16) q[t] = qkv[((long)(b * Nn + n)) * 384 + h * 16 + t];
  __syncthreads();
  const float* kp = &qkv[((long)(b * Nn + t)) * 384 + 128 + h * 16];
  float lg = 0.f;
#pragma unroll
  for (int e = 0; e < 16; ++e) lg += q[e] * kp[e];
  lg += toF(aR[(((long)(b * Hh + h) * Nn + n)) * Nn + t]);
  lg = lg * conn[((long)(b * Nn + n)) * Nn + t] * 0.25f;
  float mx = blk_max(lg, sred);
  float ex = expf(lg - mx);
  float s = blk_sum(ex, sred);
  p[t] = ex / s;
  __syncthreads();
  if (t < 16) {
    float acc = 0.f;
    const float* vp = &qkv[((long)(b * Nn)) * 384 + 256 + h * 16 + t];
    for (int m = 0; m < 256; ++m) acc += p[m] * vp[(long)m * 384];
    obuf[((long)(b * Nn + n)) * 128 + h * 16 + t] = acc;
  }
}

extern "C" void kernel_launch(void* const* d_in, const int* in_sizes, int n_in,
                              void* d_out, int out_size, void* d_ws, size_t ws_size,
                              hipStream_t stream) {
  const float* joint_in = (const float*)d_in[0];
  const float* relation_in = (const float*)d_in[1];
  const float* conn = (const float*)d_in[2];
  const float* je_w1 = (const float*)d_in[3];
  const float* je_b1 = (const float*)d_in[4];
  const float* je_w2 = (const float*)d_in[5];
  const float* je_b2 = (const float*)d_in[6];
  const float* je_w3 = (const float*)d_in[7];
  const float* je_b3 = (const float*)d_in[8];
  const float* re_w1 = (const float*)d_in[9];
  const float* re_b1 = (const float*)d_in[10];
  const float* re_w2 = (const float*)d_in[11];
  const float* re_b2 = (const float*)d_in[12];
  const float* re_w3 = (const float*)d_in[13];
  const float* re_b3 = (const float*)d_in[14];
  const float* qkv_w = (const float*)d_in[15];
  const float* qkv_b = (const float*)d_in[16];
  const float* rconv_w = (const float*)d_in[17];
  const float* rconv_b = (const float*)d_in[18];
  const float* proj_w = (const float*)d_in[19];
  const float* proj_b = (const float*)d_in[20];
  const float* ln1_g = (const float*)d_in[21];
  const float* ln1_b = (const float*)d_in[22];
  const float* ln2_g = (const float*)d_in[23];
  const float* ln2_b = (const float*)d_in[24];
  const float* ln3_g = (const float*)d_in[25];
  const float* ln3_b = (const float*)d_in[26];
  const float* mw1 = (const float*)d_in[27];
  const float* mb1 = (const float*)d_in[28];
  const float* mw2 = (const float*)d_in[29];
  const float* mb2 = (const float*)d_in[30];
  const float* ng = (const float*)d_in[31];
  const float* nb = (const float*)d_in[32];
  const float* dw1 = (const float*)d_in[33];
  const float* db1 = (const float*)d_in[34];
  const float* dw2 = (const float*)d_in[35];
  const float* db2 = (const float*)d_in[36];
  const float* dw3 = (const float*)d_in[37];
  const float* db3 = (const float*)d_in[38];

  // ---- ws carve-up ----
  char* ws = (char*)d_ws;
  size_t off = 0;
  auto alloc = [&](size_t bytes) -> void* {
    void* p = ws + off;
    off += (bytes + 255) & ~(size_t)255;
    return p;
  };
  // persistent
  bf16* attnR = (bf16*)alloc((size_t)DEPTHd * Bb * Hh * Nn * Nn * 2);  // 33.55 MB
  bf16* Wt1 = (bf16*)alloc(256 * 32 * 2);
  bf16* Wt2 = (bf16*)alloc(256 * 256 * 2);
  bf16* Wt3 = (bf16*)alloc(128 * 256 * 2);
  bf16* gWt = (bf16*)alloc(32 * 128 * 2);
  float* sgW = (float*)alloc(32 * 4);
  float* bconst = (float*)alloc(32 * 4);
  float* jf = (float*)alloc((size_t)BN * 128 * 4);
  float* xb = (float*)alloc((size_t)BN * 128 * 4);
  float* qkvb = (float*)alloc((size_t)BN * 384 * 4);
  float* obuf = (float*)alloc((size_t)BN * 128 * 4);
  float* hbuf = (float*)alloc((size_t)BN * 128 * 4);
  // arena (shared: joint-enc scratch | relation chunk bufs | decoder scratch)
  char* arena = ws + off;
  size_t avail = (ws_size > off) ? (ws_size - off) : 0;
  // per-row: bufA 512 + bufB 512 + bufC 256 + stats 8 = 1288 B
  int CH = 2048;
  for (int c = 65536; c >= 2048; c >>= 1) {
    if ((size_t)c * 1288 + 1024 <= avail) { CH = c; break; }
  }
  bf16* bufA = (bf16*)arena;                                  // CH*256 bf16
  bf16* bufB = (bf16*)(arena + (size_t)CH * 512);             // CH*256 bf16
  bf16* bufC = (bf16*)(arena + (size_t)CH * 1024);            // CH*128 bf16
  float2* stats = (float2*)(arena + (size_t)CH * 1280);       // CH float2
  float* d1 = (float*)arena;                                  // BN*256 f32
  float* d2 = (float*)(arena + (size_t)BN * 256 * 4);         // BN*512 f32

#define LIN(TIN, TOUT, GELU, inp, Wp, bp, outp, residp, rows, K, cols)              \
  k_linear<TIN, TOUT, GELU><<<dim3(((cols) + 255) / 256, (rows) / 8), dim3(256), 0, \
                              stream>>>(inp, Wp, bp, outp, residp, rows, K, cols)

  // ---- prep transposed weights + gW factors ----
  k_prep<<<dim3(256), dim3(256), 0, stream>>>(re_w1, re_w2, re_w3, ln2_g, ln2_b,
                                              rconv_w, rconv_b, Wt1, Wt2, Wt3, gWt,
                                              sgW, bconst);

  // ---- joint encoder: 96 -> 256 -> 256 -> 128 ----
  LIN(float, float, false, joint_in, je_w1, je_b1, d1, (const float*)nullptr, BN, 96, 256);
  LIN(float, float, false, d1, je_w2, je_b2, d2, (const float*)nullptr, BN, 256, 256);
  LIN(float, float, false, d2, je_w3, je_b3, jf, (const float*)nullptr, BN, 256, 128);

  // ---- relation encoder (MFMA), chunked; fused LN-stats + gW epilogue ----
  int nchunk = RTOT / CH;
  for (int ci = 0; ci < nchunk; ++ci) {
    long row0 = (long)ci * CH;
    k_gemm_mfma<float, bf16, false><<<dim3(2, CH / 128), dim3(256), 0, stream>>>(
        relation_in + row0 * 26, 26, 32, Wt1, re_b1, bufA, 256, nullptr);
    k_gemm_mfma<bf16, bf16, false><<<dim3(2, CH / 128), dim3(256), 0, stream>>>(
        bufA, 256, 256, Wt2, re_b2, bufB, 256, nullptr);
    k_gemm_mfma<bf16, bf16, true><<<dim3(1, CH / 128), dim3(256), 0, stream>>>(
        bufB, 256, 256, Wt3, re_b3, bufC, 128, stats);
    k_gemm32<<<dim3(CH / 256), dim3(256), 0, stream>>>(bufC, stats, gWt, sgW, bconst,
                                                       attnR, row0);
  }

  // ---- transformer blocks ----
  for (int d = 0; d < DEPTHd; ++d) {
    k_ln<<<dim3(BN), dim3(128), 0, stream>>>(jf, ln1_g + d * 128, ln1_b + d * 128, xb);
    LIN(float, float, false, xb, qkv_w + (size_t)d * 128 * 384, qkv_b + d * 384, qkvb,
        (const float*)nullptr, BN, 128, 384);
    k_attn<<<dim3(Nn, Hh, Bb), dim3(256), 0, stream>>>(
        qkvb, attnR + (size_t)d * Bb * Hh * Nn * Nn, conn, obuf);
    LIN(float, float, false, obuf, proj_w + (size_t)d * 128 * 128, proj_b + d * 128, jf,
        (const float*)jf, BN, 128, 128);
    k_ln<<<dim3(BN), dim3(128), 0, stream>>>(jf, ln3_g + d * 128, ln3_b + d * 128, xb);
    LIN(float, float, true, xb, mw1 + (size_t)d * 128 * 128, mb1 + d * 128, hbuf,
        (const float*)nullptr, BN, 128, 128);
    LIN(float, float, false, hbuf, mw2 + (size_t)d * 128 * 128, mb2 + d * 128, jf,
        (const float*)jf, BN, 128, 128);
  }

  // ---- final LN + decoder 128 -> 256 -> 512 -> 90 ----
  k_ln<<<dim3(BN), dim3(128), 0, stream>>>(jf, ng, nb, xb);
  LIN(float, float, false, xb, dw1, db1, d1, (const float*)nullptr, BN, 128, 256);
  LIN(float, float, false, d1, dw2, db2, d2, (const float*)nullptr, BN, 256, 512);
  LIN(float, float, false, d2, dw3, db3, (float*)d_out, (const float*)nullptr, BN, 512, 90);

#undef LIN
}

// Round 5
// 1424.162 us; speedup vs baseline: 3.8248x; 1.0777x over previous
//
#include <hip/hip_runtime.h>
#include <hip/hip_bf16.h>
#include <math.h>

typedef __hip_bfloat16 bf16;
typedef __attribute__((ext_vector_type(8))) short short8;
typedef __attribute__((ext_vector_type(4))) float f32x4;

// Problem constants
#define Bb 8
#define Nn 256
#define Cc 128
#define Hh 8
#define DEPTHd 4
#define BN 2048           // B*N
#define RTOT 524288       // B*N*N

__device__ inline float toF(float v) { return v; }
__device__ inline float toF(bf16 v) { return __bfloat162float(v); }
__device__ inline void stF(float* p, float v) { *p = v; }
__device__ inline void stF(bf16* p, float v) { *p = __float2bfloat16(v); }

// async global->LDS, 16B per lane. LDS dest is wave-uniform base + lane*16.
__device__ inline void gload16(const bf16* g, bf16* l) {
  __builtin_amdgcn_global_load_lds(
      (const __attribute__((address_space(1))) unsigned int*)g,
      (__attribute__((address_space(3))) unsigned int*)l, 16, 0, 0);
}

// ---- block reductions (blockDim.x = 128 or 256). sred >= 8 floats. ----
__device__ inline float blk_sum(float v, float* sred) {
#pragma unroll
  for (int off = 32; off; off >>= 1) v += __shfl_down(v, off, 64);
  int wid = threadIdx.x >> 6;
  int lane = threadIdx.x & 63;
  int nw = blockDim.x >> 6;
  if (lane == 0) sred[wid] = v;
  __syncthreads();
  float s = ((int)threadIdx.x < nw) ? sred[threadIdx.x] : 0.f;
  s += __shfl_down(s, 2, 64);
  s += __shfl_down(s, 1, 64);
  if (threadIdx.x == 0) sred[4] = s;
  __syncthreads();
  float r = sred[4];
  __syncthreads();
  return r;
}

__device__ inline float blk_max(float v, float* sred) {
#pragma unroll
  for (int off = 32; off; off >>= 1) v = fmaxf(v, __shfl_down(v, off, 64));
  int wid = threadIdx.x >> 6;
  int lane = threadIdx.x & 63;
  int nw = blockDim.x >> 6;
  if (lane == 0) sred[wid] = v;
  __syncthreads();
  float s = ((int)threadIdx.x < nw) ? sred[threadIdx.x] : -INFINITY;
  s = fmaxf(s, __shfl_down(s, 2, 64));
  s = fmaxf(s, __shfl_down(s, 1, 64));
  if (threadIdx.x == 0) sred[4] = s;
  __syncthreads();
  float r = sred[4];
  __syncthreads();
  return r;
}

// =============== MFMA GEMM: C[rows][cols] = A[rows][Ka] @ Wt^T + bias ===============
// Wt is pre-transposed bf16 [cols][Kp], Kp = Ka rounded up to 32.
// Tile 128x128 per block (256 thr = 4 waves in 2x2, each wave 64x64 = 4x4 mfma tiles).
// TA=bf16: Ka%32==0, global_load_lds width-16 staging. TA=float: scalar staging+pad.
// STATS (requires cols==128): also emit per-row LayerNorm stats (mean, rsqrt(var+eps)).
template <typename TA, typename TC, bool STATS>
__global__ __launch_bounds__(256) void k_gemm_mfma(
    const TA* __restrict__ A, int Ka, int Kp, const bf16* __restrict__ Bt,
    const float* __restrict__ bias, TC* __restrict__ C, int cols,
    float2* __restrict__ stats) {
  __shared__ __align__(16) bf16 sA[128 * 32];
  __shared__ __align__(16) bf16 sB[128 * 32];
  __shared__ float sstat[128][2][2];

  const int t = threadIdx.x;
  const int lane = t & 63;
  const int wv = t >> 6;
  const int wr = wv >> 1, wc = wv & 1;
  const int lrow = lane & 15, quad = lane >> 4;
  const long row0 = (long)blockIdx.y * 128;
  const int n0 = blockIdx.x * 128;
  const int rg = lane >> 2;           // 0..15: row within 16-row staging group
  const int kE = (lane & 3) * 8;      // bf16 elem offset within 32-wide K tile

  f32x4 zero = {0.f, 0.f, 0.f, 0.f};
  f32x4 acc[4][4];
#pragma unroll
  for (int i = 0; i < 4; ++i)
#pragma unroll
    for (int j = 0; j < 4; ++j) acc[i][j] = zero;

  for (int k0 = 0; k0 < Kp; k0 += 32) {
    // ---- stage B tile [128][32] via async DMA (wave wv covers rows wv*32..wv*32+31) ----
    {
      const int r0 = wv * 32;
      gload16(&Bt[(long)(n0 + r0 + rg) * Kp + k0 + kE], &sB[r0 * 32]);
      gload16(&Bt[(long)(n0 + r0 + 16 + rg) * Kp + k0 + kE], &sB[(r0 + 16) * 32]);
    }
    // ---- stage A tile [128][32] ----
    if (sizeof(TA) == 2) {
      const int r0 = wv * 32;
      gload16((const bf16*)&A[(row0 + r0 + rg) * (long)Ka + k0 + kE], &sA[r0 * 32]);
      gload16((const bf16*)&A[(row0 + r0 + 16 + rg) * (long)Ka + k0 + kE],
              &sA[(r0 + 16) * 32]);
    } else {
      for (int idx = t; idx < 128 * 32; idx += 256) {
        int r = idx >> 5, k = idx & 31;
        int gk = k0 + k;
        float v = (gk < Ka) ? toF(A[(row0 + r) * (long)Ka + gk]) : 0.f;
        sA[idx] = __float2bfloat16(v);
      }
    }
    __syncthreads();
    short8 af[4], bfr[4];
#pragma unroll
    for (int i = 0; i < 4; ++i)
      af[i] = *(const short8*)&sA[(wr * 64 + i * 16 + lrow) * 32 + quad * 8];
#pragma unroll
    for (int j = 0; j < 4; ++j)
      bfr[j] = *(const short8*)&sB[(wc * 64 + j * 16 + lrow) * 32 + quad * 8];
#pragma unroll
    for (int i = 0; i < 4; ++i)
#pragma unroll
      for (int j = 0; j < 4; ++j)
        acc[i][j] =
            __builtin_amdgcn_mfma_f32_16x16x32_bf16(af[i], bfr[j], acc[i][j], 0, 0, 0);
    __syncthreads();
  }

  // ---- epilogue: bias add, store, optional LN stats ----
#pragma unroll
  for (int i = 0; i < 4; ++i) {
#pragma unroll
    for (int r = 0; r < 4; ++r) {
      int rl = wr * 64 + i * 16 + quad * 4 + r;
      long gr = row0 + rl;
      float s1 = 0.f, s2 = 0.f;
#pragma unroll
      for (int j = 0; j < 4; ++j) {
        int gc = n0 + wc * 64 + j * 16 + lrow;
        float v = acc[i][j][r] + bias[gc];
        stF(&C[gr * cols + gc], v);
        if (STATS) { s1 += v; s2 += v * v; }
      }
      if (STATS) {
#pragma unroll
        for (int m = 1; m < 16; m <<= 1) {
          s1 += __shfl_xor(s1, m, 64);
          s2 += __shfl_xor(s2, m, 64);
        }
        if (lrow == 0) {
          sstat[rl][wc][0] = s1;
          sstat[rl][wc][1] = s2;
        }
      }
    }
  }
  if (STATS) {
    __syncthreads();
    if (t < 128) {
      float s1 = sstat[t][0][0] + sstat[t][1][0];
      float s2 = sstat[t][0][1] + sstat[t][1][1];
      float mu = s1 * (1.f / 128.f);
      float var = s2 * (1.f / 128.f) - mu * mu;
      stats[row0 + t] = make_float2(mu, rsqrtf(var + 1e-5f));
    }
  }
}

// =============== gemm32 (transposed): D[32 cols][256 rows] = gWt @ X^T ===============
// LDS-free. D-layout makes attnR stores contiguous along m (16 lanes x 32B segments).
// out = inv*(acc - mu*sgW[col]) + bconst[col]; scatter into attnR[d][b][h][n][m].
__global__ __launch_bounds__(256) void k_gemm32(
    const bf16* __restrict__ X, const float2* __restrict__ stats,
    const bf16* __restrict__ gWt, const float* __restrict__ sgW,
    const float* __restrict__ bconst, bf16* __restrict__ attnR, long row0g) {
  const int t = threadIdx.x;
  const int lane = t & 63, wv = t >> 6;
  const int lrow = lane & 15, quad = lane >> 4;
  const long rb = (long)blockIdx.x * 256;

  f32x4 zero = {0.f, 0.f, 0.f, 0.f};
  f32x4 acc[2][4];  // [mt: 16-col tile][nt: 16-row tile]
#pragma unroll
  for (int mt = 0; mt < 2; ++mt)
#pragma unroll
    for (int nt = 0; nt < 4; ++nt) acc[mt][nt] = zero;

  for (int k0 = 0; k0 < 128; k0 += 32) {
    short8 af[2], bfr[4];
#pragma unroll
    for (int mt = 0; mt < 2; ++mt)
      af[mt] = *(const short8*)&gWt[(mt * 16 + lrow) * 128 + k0 + quad * 8];
#pragma unroll
    for (int nt = 0; nt < 4; ++nt)
      bfr[nt] =
          *(const short8*)&X[(rb + wv * 64 + nt * 16 + lrow) * 128 + k0 + quad * 8];
#pragma unroll
    for (int mt = 0; mt < 2; ++mt)
#pragma unroll
      for (int nt = 0; nt < 4; ++nt)
        acc[mt][nt] =
            __builtin_amdgcn_mfma_f32_16x16x32_bf16(af[mt], bfr[nt], acc[mt][nt], 0, 0, 0);
  }

#pragma unroll
  for (int nt = 0; nt < 4; ++nt) {
    long grl = rb + wv * 64 + nt * 16 + lrow;
    float2 st = stats[grl];
    long gr = row0g + grl;
    int bb = (int)(gr >> 16);
    int nn = (int)((gr >> 8) & 255);
    int mm = (int)(gr & 255);
#pragma unroll
    for (int mt = 0; mt < 2; ++mt) {
#pragma unroll
      for (int reg = 0; reg < 4; ++reg) {
        int col = mt * 16 + quad * 4 + reg;
        float v = st.y * (acc[mt][nt][reg] - st.x * sgW[col]) + bconst[col];
        int dd = col >> 3, hh = col & 7;
        attnR[(((long)(dd * Bb + bb) * Hh + hh) * Nn + nn) * Nn + mm] =
            __float2bfloat16(v);
      }
    }
  }
}

// ---- prep: transpose+cast weights, build gW / sgW / bconst ----
__global__ void k_prep(const float* __restrict__ re_w1, const float* __restrict__ re_w2,
                       const float* __restrict__ re_w3, const float* __restrict__ ln2_g,
                       const float* __restrict__ ln2_b, const float* __restrict__ rconv_w,
                       const float* __restrict__ rconv_b, bf16* __restrict__ Wt1,
                       bf16* __restrict__ Wt2, bf16* __restrict__ Wt3,
                       bf16* __restrict__ gWt, float* __restrict__ sgW,
                       float* __restrict__ bconst) {
  int idx = blockIdx.x * 256 + threadIdx.x;
  if (idx < 65536) {
    int n = idx >> 8, k = idx & 255;
    Wt2[n * 256 + k] = __float2bfloat16(re_w2[k * 256 + n]);
  }
  if (idx < 32768) {
    int n = idx >> 8, k = idx & 255;
    Wt3[n * 256 + k] = __float2bfloat16(re_w3[k * 128 + n]);
  }
  if (idx < 8192) {
    int n = idx >> 5, k = idx & 31;
    Wt1[n * 32 + k] = __float2bfloat16((k < 26) ? re_w1[k * 256 + n] : 0.f);
  }
  if (idx < 4096) {
    int col = idx >> 7, c = idx & 127;
    int dd = col >> 3, h = col & 7;
    gWt[col * 128 + c] =
        __float2bfloat16(ln2_g[dd * 128 + c] * rconv_w[(dd * 128 + c) * 8 + h]);
  }
  if (idx < 32) {
    int dd = idx >> 3, h = idx & 7;
    float sg = 0.f, bc = 0.f;
    for (int c = 0; c < 128; ++c) {
      float w = rconv_w[(dd * 128 + c) * 8 + h];
      sg += ln2_g[dd * 128 + c] * w;
      bc += ln2_b[dd * 128 + c] * w;
    }
    sgW[idx] = sg;
    bconst[idx] = bc + rconv_b[idx];
  }
}

// ---- generic linear (VALU) for the small joint/transformer/decoder GEMMs ----
template <typename TIN, typename TOUT, bool GELU>
__global__ void k_linear(const TIN* __restrict__ in, const float* __restrict__ W,
                         const float* __restrict__ bias, TOUT* __restrict__ out,
                         const float* __restrict__ resid, int rows, int K, int cols) {
  __shared__ float sin_[8 * 512];
  int t = threadIdx.x;
  int row0 = blockIdx.y * 8;
  int RK = 8 * K;
  for (int idx = t; idx < RK; idx += 256) {
    int r = idx / K;
    int k = idx - r * K;
    int row = row0 + r;
    sin_[idx] = (row < rows) ? toF(in[(long)row * K + k]) : 0.f;
  }
  __syncthreads();
  int c = blockIdx.x * 256 + t;
  if (c >= cols) return;
  float acc[8] = {0.f, 0.f, 0.f, 0.f, 0.f, 0.f, 0.f, 0.f};
  const float* wp = W + c;
#pragma unroll 4
  for (int k = 0; k < K; ++k) {
    float wv = wp[(long)k * cols];
#pragma unroll
    for (int r = 0; r < 8; ++r) acc[r] += sin_[r * K + k] * wv;
  }
  float bv = bias[c];
#pragma unroll
  for (int r = 0; r < 8; ++r) {
    int row = row0 + r;
    if (row < rows) {
      float v = acc[r] + bv;
      if (GELU) v = 0.5f * v * (1.f + erff(v * 0.70710678118654752f));
      if (resid) v += resid[(long)row * cols + c];
      stF(&out[(long)row * cols + c], v);
    }
  }
}

// ---- LayerNorm over last dim 128 ----
__global__ void k_ln(const float* __restrict__ in, const float* __restrict__ g,
                     const float* __restrict__ b, float* __restrict__ out) {
  __shared__ float sred[8];
  int row = blockIdx.x;
  int t = threadIdx.x;
  float x = in[(long)row * 128 + t];
  float mean = blk_sum(x, sred) * (1.f / 128.f);
  float d = x - mean;
  float var = blk_sum(d * d, sred) * (1.f / 128.f);
  out[(long)row * 128 + t] = d * rsqrtf(var + 1e-5f) * g[t] + b[t];
}

// ---- fused attention for one depth: logits + conn + softmax + AV ----
// grid = (N, H, B), block = 256. AV: group g (16 thr-groups) x elem e.
__global__ void k_attn(const float* __restrict__ qkv, const bf16* __restrict__ aR,
                       const float* __restrict__ conn, float* __restrict__ obuf) {
  __shared__ float q[16];
  __shared__ float p[256];
  __shared__ float sred[8];
  __shared__ float pv[16][17];
  int n = blockIdx.x, h = blockIdx.y, b = blockIdx.z;
  int t = threadIdx.x;
  if (t < 16) q[t] = qkv[((long)(b * Nn + n)) * 384 + h * 16 + t];
  __syncthreads();
  const float* kp = &qkv[((long)(b * Nn + t)) * 384 + 128 + h * 16];
  float lg = 0.f;
#pragma unroll
  for (int e = 0; e < 16; ++e) lg += q[e] * kp[e];
  lg += toF(aR[(((long)(b * Hh + h) * Nn + n)) * Nn + t]);
  lg = lg * conn[((long)(b * Nn + n)) * Nn + t] * 0.25f;
  float mx = blk_max(lg, sred);
  float ex = expf(lg - mx);
  float s = blk_sum(ex, sred);
  p[t] = ex / s;
  __syncthreads();
  // AV: thread (g,e) accumulates 16 m-values for output elem e
  int g = t >> 4, e = t & 15;
  const float* vp = &qkv[((long)(b * Nn + g * 16)) * 384 + 256 + h * 16 + e];
  float acc = 0.f;
#pragma unroll
  for (int mi = 0; mi < 16; ++mi) acc += p[g * 16 + mi] * vp[(long)mi * 384];
  pv[g][e] = acc;
  __syncthreads();
  if (t < 16) {
    float s2 = 0.f;
#pragma unroll
    for (int gg = 0; gg < 16; ++gg) s2 += pv[gg][t];
    obuf[((long)(b * Nn + n)) * 128 + h * 16 + t] = s2;
  }
}

extern "C" void kernel_launch(void* const* d_in, const int* in_sizes, int n_in,
                              void* d_out, int out_size, void* d_ws, size_t ws_size,
                              hipStream_t stream) {
  const float* joint_in = (const float*)d_in[0];
  const float* relation_in = (const float*)d_in[1];
  const float* conn = (const float*)d_in[2];
  const float* je_w1 = (const float*)d_in[3];
  const float* je_b1 = (const float*)d_in[4];
  const float* je_w2 = (const float*)d_in[5];
  const float* je_b2 = (const float*)d_in[6];
  const float* je_w3 = (const float*)d_in[7];
  const float* je_b3 = (const float*)d_in[8];
  const float* re_w1 = (const float*)d_in[9];
  const float* re_b1 = (const float*)d_in[10];
  const float* re_w2 = (const float*)d_in[11];
  const float* re_b2 = (const float*)d_in[12];
  const float* re_w3 = (const float*)d_in[13];
  const float* re_b3 = (const float*)d_in[14];
  const float* qkv_w = (const float*)d_in[15];
  const float* qkv_b = (const float*)d_in[16];
  const float* rconv_w = (const float*)d_in[17];
  const float* rconv_b = (const float*)d_in[18];
  const float* proj_w = (const float*)d_in[19];
  const float* proj_b = (const float*)d_in[20];
  const float* ln1_g = (const float*)d_in[21];
  const float* ln1_b = (const float*)d_in[22];
  const float* ln2_g = (const float*)d_in[23];
  const float* ln2_b = (const float*)d_in[24];
  const float* ln3_g = (const float*)d_in[25];
  const float* ln3_b = (const float*)d_in[26];
  const float* mw1 = (const float*)d_in[27];
  const float* mb1 = (const float*)d_in[28];
  const float* mw2 = (const float*)d_in[29];
  const float* mb2 = (const float*)d_in[30];
  const float* ng = (const float*)d_in[31];
  const float* nb = (const float*)d_in[32];
  const float* dw1 = (const float*)d_in[33];
  const float* db1 = (const float*)d_in[34];
  const float* dw2 = (const float*)d_in[35];
  const float* db2 = (const float*)d_in[36];
  const float* dw3 = (const float*)d_in[37];
  const float* db3 = (const float*)d_in[38];

  // ---- ws carve-up ----
  char* ws = (char*)d_ws;
  size_t off = 0;
  auto alloc = [&](size_t bytes) -> void* {
    void* p = ws + off;
    off += (bytes + 255) & ~(size_t)255;
    return p;
  };
  // persistent
  bf16* attnR = (bf16*)alloc((size_t)DEPTHd * Bb * Hh * Nn * Nn * 2);  // 33.55 MB
  bf16* Wt1 = (bf16*)alloc(256 * 32 * 2);
  bf16* Wt2 = (bf16*)alloc(256 * 256 * 2);
  bf16* Wt3 = (bf16*)alloc(128 * 256 * 2);
  bf16* gWt = (bf16*)alloc(32 * 128 * 2);
  float* sgW = (float*)alloc(32 * 4);
  float* bconst = (float*)alloc(32 * 4);
  float* jf = (float*)alloc((size_t)BN * 128 * 4);
  float* xb = (float*)alloc((size_t)BN * 128 * 4);
  float* qkvb = (float*)alloc((size_t)BN * 384 * 4);
  float* obuf = (float*)alloc((size_t)BN * 128 * 4);
  float* hbuf = (float*)alloc((size_t)BN * 128 * 4);
  // arena (shared: joint-enc scratch | relation chunk bufs | decoder scratch)
  char* arena = ws + off;
  size_t avail = (ws_size > off) ? (ws_size - off) : 0;
  // per-row: bufA 512 + bufB 512 + bufC 256 + stats 8 = 1288 B
  int CH = 2048;
  for (int c = 65536; c >= 2048; c >>= 1) {
    if ((size_t)c * 1288 + 1024 <= avail) { CH = c; break; }
  }
  bf16* bufA = (bf16*)arena;                                  // CH*256 bf16
  bf16* bufB = (bf16*)(arena + (size_t)CH * 512);             // CH*256 bf16
  bf16* bufC = (bf16*)(arena + (size_t)CH * 1024);            // CH*128 bf16
  float2* stats = (float2*)(arena + (size_t)CH * 1280);       // CH float2
  float* d1 = (float*)arena;                                  // BN*256 f32
  float* d2 = (float*)(arena + (size_t)BN * 256 * 4);         // BN*512 f32

#define LIN(TIN, TOUT, GELU, inp, Wp, bp, outp, residp, rows, K, cols)              \
  k_linear<TIN, TOUT, GELU><<<dim3(((cols) + 255) / 256, (rows) / 8), dim3(256), 0, \
                              stream>>>(inp, Wp, bp, outp, residp, rows, K, cols)

  // ---- prep transposed weights + gW factors ----
  k_prep<<<dim3(256), dim3(256), 0, stream>>>(re_w1, re_w2, re_w3, ln2_g, ln2_b,
                                              rconv_w, rconv_b, Wt1, Wt2, Wt3, gWt,
                                              sgW, bconst);

  // ---- joint encoder: 96 -> 256 -> 256 -> 128 ----
  LIN(float, float, false, joint_in, je_w1, je_b1, d1, (const float*)nullptr, BN, 96, 256);
  LIN(float, float, false, d1, je_w2, je_b2, d2, (const float*)nullptr, BN, 256, 256);
  LIN(float, float, false, d2, je_w3, je_b3, jf, (const float*)nullptr, BN, 256, 128);

  // ---- relation encoder (MFMA), chunked; fused LN-stats + gW epilogue ----
  int nchunk = RTOT / CH;
  for (int ci = 0; ci < nchunk; ++ci) {
    long row0 = (long)ci * CH;
    k_gemm_mfma<float, bf16, false><<<dim3(2, CH / 128), dim3(256), 0, stream>>>(
        relation_in + row0 * 26, 26, 32, Wt1, re_b1, bufA, 256, nullptr);
    k_gemm_mfma<bf16, bf16, false><<<dim3(2, CH / 128), dim3(256), 0, stream>>>(
        bufA, 256, 256, Wt2, re_b2, bufB, 256, nullptr);
    k_gemm_mfma<bf16, bf16, true><<<dim3(1, CH / 128), dim3(256), 0, stream>>>(
        bufB, 256, 256, Wt3, re_b3, bufC, 128, stats);
    k_gemm32<<<dim3(CH / 256), dim3(256), 0, stream>>>(bufC, stats, gWt, sgW, bconst,
                                                       attnR, row0);
  }

  // ---- transformer blocks ----
  for (int d = 0; d < DEPTHd; ++d) {
    k_ln<<<dim3(BN), dim3(128), 0, stream>>>(jf, ln1_g + d * 128, ln1_b + d * 128, xb);
    LIN(float, float, false, xb, qkv_w + (size_t)d * 128 * 384, qkv_b + d * 384, qkvb,
        (const float*)nullptr, BN, 128, 384);
    k_attn<<<dim3(Nn, Hh, Bb), dim3(256), 0, stream>>>(
        qkvb, attnR + (size_t)d * Bb * Hh * Nn * Nn, conn, obuf);
    LIN(float, float, false, obuf, proj_w + (size_t)d * 128 * 128, proj_b + d * 128, jf,
        (const float*)jf, BN, 128, 128);
    k_ln<<<dim3(BN), dim3(128), 0, stream>>>(jf, ln3_g + d * 128, ln3_b + d * 128, xb);
    LIN(float, float, true, xb, mw1 + (size_t)d * 128 * 128, mb1 + d * 128, hbuf,
        (const float*)nullptr, BN, 128, 128);
    LIN(float, float, false, hbuf, mw2 + (size_t)d * 128 * 128, mb2 + d * 128, jf,
        (const float*)jf, BN, 128, 128);
  }

  // ---- final LN + decoder 128 -> 256 -> 512 -> 90 ----
  k_ln<<<dim3(BN), dim3(128), 0, stream>>>(jf, ng, nb, xb);
  LIN(float, float, false, xb, dw1, db1, d1, (const float*)nullptr, BN, 128, 256);
  LIN(float, float, false, d1, dw2, db2, d2, (const float*)nullptr, BN, 256, 512);
  LIN(float, float, false, d2, dw3, db3, (float*)d_out, (const float*)nullptr, BN, 512, 90);

#undef LIN
}

// Round 6
// 1151.243 us; speedup vs baseline: 4.7315x; 1.2371x over previous
//
#include <hip/hip_runtime.h>
#include <hip/hip_bf16.h>
#include <math.h>

typedef __hip_bfloat16 bf16;
typedef __attribute__((ext_vector_type(8))) short short8;
typedef __attribute__((ext_vector_type(4))) float f32x4;

// Problem constants
#define Bb 8
#define Nn 256
#define Cc 128
#define Hh 8
#define DEPTHd 4
#define BN 2048           // B*N
#define RTOT 524288       // B*N*N
#define X1S 264           // x1/x2 LDS row stride (bf16): 256+8 breaks 512B bank wrap
#define X3S 136           // x3 LDS row stride

__device__ inline float toF(float v) { return v; }
__device__ inline float toF(bf16 v) { return __bfloat162float(v); }
__device__ inline void stF(float* p, float v) { *p = v; }
__device__ inline void stF(bf16* p, float v) { *p = __float2bfloat16(v); }

// async global->LDS, 16B per lane. LDS dest is wave-uniform base + lane*16.
__device__ inline void gload16(const bf16* g, bf16* l) {
  __builtin_amdgcn_global_load_lds(
      (const __attribute__((address_space(1))) unsigned int*)g,
      (__attribute__((address_space(3))) unsigned int*)l, 16, 0, 0);
}

// ---- block reductions (blockDim.x = 128 or 256). sred >= 8 floats. ----
__device__ inline float blk_sum(float v, float* sred) {
#pragma unroll
  for (int off = 32; off; off >>= 1) v += __shfl_down(v, off, 64);
  int wid = threadIdx.x >> 6;
  int lane = threadIdx.x & 63;
  int nw = blockDim.x >> 6;
  if (lane == 0) sred[wid] = v;
  __syncthreads();
  float s = ((int)threadIdx.x < nw) ? sred[threadIdx.x] : 0.f;
  s += __shfl_down(s, 2, 64);
  s += __shfl_down(s, 1, 64);
  if (threadIdx.x == 0) sred[4] = s;
  __syncthreads();
  float r = sred[4];
  __syncthreads();
  return r;
}

__device__ inline float blk_max(float v, float* sred) {
#pragma unroll
  for (int off = 32; off; off >>= 1) v = fmaxf(v, __shfl_down(v, off, 64));
  int wid = threadIdx.x >> 6;
  int lane = threadIdx.x & 63;
  int nw = blockDim.x >> 6;
  if (lane == 0) sred[wid] = v;
  __syncthreads();
  float s = ((int)threadIdx.x < nw) ? sred[threadIdx.x] : -INFINITY;
  s = fmaxf(s, __shfl_down(s, 2, 64));
  s = fmaxf(s, __shfl_down(s, 1, 64));
  if (threadIdx.x == 0) sred[4] = s;
  __syncthreads();
  float r = sred[4];
  __syncthreads();
  return r;
}

// =============== MFMA GEMM: C[rows][ncols] = act(A[rows][Ka] @ Bt^T + bias) (+resid) ===============
// Bt = bf16 [colsPad][Kp] (colsPad = grid.x*128). Tile 128x128/block, 4 waves 2x2.
// TA=bf16: Ka%32==0, async global_load_lds staging. TA=float: scalar staging + K zero-pad.
template <typename TA, typename TC, bool GELU, bool RESID>
__global__ __launch_bounds__(256) void k_gemm_mfma(
    const TA* __restrict__ A, int Ka, int Kp, const bf16* __restrict__ Bt,
    const float* __restrict__ bias, TC* __restrict__ C, int ldc, int ncols,
    const float* __restrict__ resid) {
  __shared__ __align__(16) bf16 sA[128 * 32];
  __shared__ __align__(16) bf16 sB[128 * 32];

  const int t = threadIdx.x;
  const int lane = t & 63;
  const int wv = t >> 6;
  const int wr = wv >> 1, wc = wv & 1;
  const int lrow = lane & 15, quad = lane >> 4;
  const long row0 = (long)blockIdx.y * 128;
  const int n0 = blockIdx.x * 128;
  const int rg = lane >> 2;
  const int kE = (lane & 3) * 8;

  f32x4 zero = {0.f, 0.f, 0.f, 0.f};
  f32x4 acc[4][4];
#pragma unroll
  for (int i = 0; i < 4; ++i)
#pragma unroll
    for (int j = 0; j < 4; ++j) acc[i][j] = zero;

  for (int k0 = 0; k0 < Kp; k0 += 32) {
    {
      const int r0 = wv * 32;
      gload16(&Bt[(long)(n0 + r0 + rg) * Kp + k0 + kE], &sB[r0 * 32]);
      gload16(&Bt[(long)(n0 + r0 + 16 + rg) * Kp + k0 + kE], &sB[(r0 + 16) * 32]);
    }
    if (sizeof(TA) == 2) {
      const int r0 = wv * 32;
      gload16((const bf16*)&A[(row0 + r0 + rg) * (long)Ka + k0 + kE], &sA[r0 * 32]);
      gload16((const bf16*)&A[(row0 + r0 + 16 + rg) * (long)Ka + k0 + kE],
              &sA[(r0 + 16) * 32]);
    } else {
      for (int idx = t; idx < 128 * 32; idx += 256) {
        int r = idx >> 5, k = idx & 31;
        int gk = k0 + k;
        float v = (gk < Ka) ? toF(A[(row0 + r) * (long)Ka + gk]) : 0.f;
        sA[idx] = __float2bfloat16(v);
      }
    }
    __syncthreads();
    short8 af[4], bfr[4];
#pragma unroll
    for (int i = 0; i < 4; ++i)
      af[i] = *(const short8*)&sA[(wr * 64 + i * 16 + lrow) * 32 + quad * 8];
#pragma unroll
    for (int j = 0; j < 4; ++j)
      bfr[j] = *(const short8*)&sB[(wc * 64 + j * 16 + lrow) * 32 + quad * 8];
#pragma unroll
    for (int i = 0; i < 4; ++i)
#pragma unroll
      for (int j = 0; j < 4; ++j)
        acc[i][j] =
            __builtin_amdgcn_mfma_f32_16x16x32_bf16(af[i], bfr[j], acc[i][j], 0, 0, 0);
    __syncthreads();
  }

#pragma unroll
  for (int i = 0; i < 4; ++i) {
#pragma unroll
    for (int r = 0; r < 4; ++r) {
      int rl = wr * 64 + i * 16 + quad * 4 + r;
      long gr = row0 + rl;
#pragma unroll
      for (int j = 0; j < 4; ++j) {
        int gc = n0 + wc * 64 + j * 16 + lrow;
        if (gc < ncols) {
          float v = acc[i][j][r] + bias[gc];
          if (GELU) v = 0.5f * v * (1.f + erff(v * 0.70710678118654752f));
          if (RESID) v += resid[gr * (long)ldc + gc];
          stF(&C[gr * (long)ldc + gc], v);
        }
      }
    }
  }
}

// =============== fully fused relation encoder + LN2 + rconv -> attnR ===============
// Block = 64 rows, 256 thr (4 waves). L1 (26->256) -> x1 LDS -> L2 (256->256) -> x2 LDS
// -> L3 (256->128)+LN stats -> x3 LDS -> gemm32 (128->32) -> attnR scatter.
// B-operands read directly from L2-resident global weights (no staging barriers).
__global__ __launch_bounds__(256) void k_relfused(
    const float* __restrict__ rin, const bf16* __restrict__ Wt1,
    const float* __restrict__ b1, const bf16* __restrict__ Wt2,
    const float* __restrict__ b2, const bf16* __restrict__ Wt3,
    const float* __restrict__ b3, const bf16* __restrict__ gWt,
    const float* __restrict__ sgW, const float* __restrict__ bconst,
    bf16* __restrict__ attnR) {
  __shared__ __align__(16) char smem[67584];  // x1 [0,33792) | x2 [33792,67584)
  bf16* x1 = (bf16*)smem;                     // [64][264]
  bf16* x2 = (bf16*)(smem + 33792);           // [64][264]
  bf16* x3 = x1;                              // [64][136] (x1 dead after L2)
  float* sstat = (float*)(smem + 18432);      // [64][4][2] partial sums
  float* sstatF = (float*)(smem + 20480);     // [64][2] (mu, inv)
  bf16* sA0 = x2;                             // [64][32] staging (x2 not yet live)

  const int t = threadIdx.x;
  const int lane = t & 63, wv = t >> 6;
  const int lrow = lane & 15, quad = lane >> 4;
  const long r0 = (long)blockIdx.x * 64;

  // stage relation_in [64][26] f32 -> sA0 bf16 [64][32]
  for (int idx = t; idx < 64 * 32; idx += 256) {
    int r = idx >> 5, k = idx & 31;
    sA0[idx] = __float2bfloat16(k < 26 ? rin[(r0 + r) * 26 + k] : 0.f);
  }
  __syncthreads();

  // ---- L1: x1[64][256] = A0 @ Wt1^T + b1 (K=32) ----
  {
    short8 af[4], bfr[4];
#pragma unroll
    for (int i = 0; i < 4; ++i)
      af[i] = *(const short8*)&sA0[(i * 16 + lrow) * 32 + quad * 8];
#pragma unroll
    for (int j = 0; j < 4; ++j)
      bfr[j] = *(const short8*)&Wt1[(wv * 64 + j * 16 + lrow) * 32 + quad * 8];
    f32x4 acc[4][4];
#pragma unroll
    for (int i = 0; i < 4; ++i)
#pragma unroll
      for (int j = 0; j < 4; ++j) {
        f32x4 z = {0.f, 0.f, 0.f, 0.f};
        acc[i][j] = __builtin_amdgcn_mfma_f32_16x16x32_bf16(af[i], bfr[j], z, 0, 0, 0);
      }
    __syncthreads();  // all waves done reading sA0 (aliases x2? no, x1 writes only) & before x1 reads
#pragma unroll
    for (int i = 0; i < 4; ++i)
#pragma unroll
      for (int j = 0; j < 4; ++j) {
        int col = wv * 64 + j * 16 + lrow;
        float bv = b1[col];
#pragma unroll
        for (int r = 0; r < 4; ++r) {
          int row = i * 16 + quad * 4 + r;
          x1[row * X1S + col] = __float2bfloat16(acc[i][j][r] + bv);
        }
      }
  }
  __syncthreads();

  // ---- L2: x2[64][256] = x1 @ Wt2^T + b2 (K=256) ----
  {
    f32x4 acc[4][4];
#pragma unroll
    for (int i = 0; i < 4; ++i)
#pragma unroll
      for (int j = 0; j < 4; ++j) {
        f32x4 z = {0.f, 0.f, 0.f, 0.f};
        acc[i][j] = z;
      }
    for (int k0 = 0; k0 < 256; k0 += 32) {
      short8 af[4], bfr[4];
#pragma unroll
      for (int i = 0; i < 4; ++i)
        af[i] = *(const short8*)&x1[(i * 16 + lrow) * X1S + k0 + quad * 8];
#pragma unroll
      for (int j = 0; j < 4; ++j)
        bfr[j] = *(const short8*)&Wt2[(wv * 64 + j * 16 + lrow) * 256 + k0 + quad * 8];
#pragma unroll
      for (int i = 0; i < 4; ++i)
#pragma unroll
        for (int j = 0; j < 4; ++j)
          acc[i][j] =
              __builtin_amdgcn_mfma_f32_16x16x32_bf16(af[i], bfr[j], acc[i][j], 0, 0, 0);
    }
    // x2 writes don't clobber x1 (disjoint), sA0 alias is dead -> no barrier needed
#pragma unroll
    for (int i = 0; i < 4; ++i)
#pragma unroll
      for (int j = 0; j < 4; ++j) {
        int col = wv * 64 + j * 16 + lrow;
        float bv = b2[col];
#pragma unroll
        for (int r = 0; r < 4; ++r) {
          int row = i * 16 + quad * 4 + r;
          x2[row * X1S + col] = __float2bfloat16(acc[i][j][r] + bv);
        }
      }
  }
  __syncthreads();  // all waves done with x1 reads + x2 writes

  // ---- L3: x3[64][128] = x2 @ Wt3^T + b3 (K=256), wave cols wv*32..+31, + LN stats ----
  {
    f32x4 acc[4][2];
#pragma unroll
    for (int i = 0; i < 4; ++i) {
      f32x4 z = {0.f, 0.f, 0.f, 0.f};
      acc[i][0] = z;
      acc[i][1] = z;
    }
    for (int k0 = 0; k0 < 256; k0 += 32) {
      short8 af[4], bfr[2];
#pragma unroll
      for (int i = 0; i < 4; ++i)
        af[i] = *(const short8*)&x2[(i * 16 + lrow) * X1S + k0 + quad * 8];
#pragma unroll
      for (int j = 0; j < 2; ++j)
        bfr[j] = *(const short8*)&Wt3[(wv * 32 + j * 16 + lrow) * 256 + k0 + quad * 8];
#pragma unroll
      for (int i = 0; i < 4; ++i)
#pragma unroll
        for (int j = 0; j < 2; ++j)
          acc[i][j] =
              __builtin_amdgcn_mfma_f32_16x16x32_bf16(af[i], bfr[j], acc[i][j], 0, 0, 0);
    }
#pragma unroll
    for (int i = 0; i < 4; ++i) {
#pragma unroll
      for (int r = 0; r < 4; ++r) {
        int row = i * 16 + quad * 4 + r;
        float v0 = acc[i][0][r] + b3[wv * 32 + lrow];
        float v1 = acc[i][1][r] + b3[wv * 32 + 16 + lrow];
        x3[row * X3S + wv * 32 + lrow] = __float2bfloat16(v0);
        x3[row * X3S + wv * 32 + 16 + lrow] = __float2bfloat16(v1);
        float s1 = v0 + v1, s2 = v0 * v0 + v1 * v1;
#pragma unroll
        for (int m = 1; m < 16; m <<= 1) {
          s1 += __shfl_xor(s1, m, 64);
          s2 += __shfl_xor(s2, m, 64);
        }
        if (lrow == 0) {
          sstat[(row * 4 + wv) * 2] = s1;
          sstat[(row * 4 + wv) * 2 + 1] = s2;
        }
      }
    }
  }
  __syncthreads();
  if (t < 64) {
    float s1 = 0.f, s2 = 0.f;
#pragma unroll
    for (int w = 0; w < 4; ++w) {
      s1 += sstat[(t * 4 + w) * 2];
      s2 += sstat[(t * 4 + w) * 2 + 1];
    }
    float mu = s1 * (1.f / 128.f);
    float var = s2 * (1.f / 128.f) - mu * mu;
    sstatF[t * 2] = mu;
    sstatF[t * 2 + 1] = rsqrtf(var + 1e-5f);
  }
  __syncthreads();

  // ---- gemm32: D[32][16 rows/wave] = gW @ x3^T, LN via stats trick, scatter ----
  {
    f32x4 acc2[2];
    {
      f32x4 z = {0.f, 0.f, 0.f, 0.f};
      acc2[0] = z;
      acc2[1] = z;
    }
    for (int k0 = 0; k0 < 128; k0 += 32) {
      short8 a0 = *(const short8*)&gWt[(lrow)*128 + k0 + quad * 8];
      short8 a1 = *(const short8*)&gWt[(16 + lrow) * 128 + k0 + quad * 8];
      short8 bb = *(const short8*)&x3[(wv * 16 + lrow) * X3S + k0 + quad * 8];
      acc2[0] = __builtin_amdgcn_mfma_f32_16x16x32_bf16(a0, bb, acc2[0], 0, 0, 0);
      acc2[1] = __builtin_amdgcn_mfma_f32_16x16x32_bf16(a1, bb, acc2[1], 0, 0, 0);
    }
    int drow = wv * 16 + lrow;
    long gr = r0 + drow;
    float mu = sstatF[drow * 2], inv = sstatF[drow * 2 + 1];
    int bb_ = (int)(gr >> 16);
    int nn = (int)((gr >> 8) & 255);
    int mm = (int)(gr & 255);
#pragma unroll
    for (int mt = 0; mt < 2; ++mt) {
#pragma unroll
      for (int reg = 0; reg < 4; ++reg) {
        int col = mt * 16 + quad * 4 + reg;
        float v = inv * (acc2[mt][reg] - mu * sgW[col]) + bconst[col];
        int dd = col >> 3, hh = col & 7;
        attnR[((((long)dd * Bb + bb_) * Hh + hh) * Nn + nn) * Nn + mm] =
            __float2bfloat16(v);
      }
    }
  }
}

// ---- prep: transpose+cast all weights to bf16 [col][K]; build gW / sgW / bconst ----
__global__ void k_prep(const float* re_w1, const float* re_w2, const float* re_w3,
                       const float* ln2_g, const float* ln2_b, const float* rconv_w,
                       const float* rconv_b, const float* je_w1, const float* je_w2,
                       const float* je_w3, const float* qkv_w, const float* proj_w,
                       const float* mw1, const float* mw2, const float* dw1,
                       const float* dw2, const float* dw3, bf16* Wt1, bf16* Wt2,
                       bf16* Wt3, bf16* gWt, float* sgW, float* bconst, bf16* Wj1,
                       bf16* Wj2, bf16* Wj3, bf16* Wq, bf16* Wp, bf16* Wm1, bf16* Wm2,
                       bf16* Wd1, bf16* Wd2, bf16* Wd3) {
  const int stride = gridDim.x * blockDim.x;
  const int tid = blockIdx.x * blockDim.x + threadIdx.x;
  for (int i = tid; i < 256 * 32; i += stride) {
    int n = i >> 5, k = i & 31;
    Wt1[i] = __float2bfloat16(k < 26 ? re_w1[k * 256 + n] : 0.f);
  }
  for (int i = tid; i < 256 * 256; i += stride) {
    int n = i >> 8, k = i & 255;
    Wt2[i] = __float2bfloat16(re_w2[k * 256 + n]);
  }
  for (int i = tid; i < 128 * 256; i += stride) {
    int n = i >> 8, k = i & 255;
    Wt3[i] = __float2bfloat16(re_w3[k * 128 + n]);
  }
  for (int i = tid; i < 32 * 128; i += stride) {
    int col = i >> 7, c = i & 127;
    int dd = col >> 3, h = col & 7;
    gWt[i] = __float2bfloat16(ln2_g[dd * 128 + c] * rconv_w[(dd * 128 + c) * 8 + h]);
  }
  if (tid < 32) {
    int dd = tid >> 3, h = tid & 7;
    float sg = 0.f, bc = 0.f;
    for (int c = 0; c < 128; ++c) {
      float w = rconv_w[(dd * 128 + c) * 8 + h];
      sg += ln2_g[dd * 128 + c] * w;
      bc += ln2_b[dd * 128 + c] * w;
    }
    sgW[tid] = sg;
    bconst[tid] = bc + rconv_b[tid];
  }
  for (int i = tid; i < 256 * 96; i += stride) {
    int n = i / 96, k = i - n * 96;
    Wj1[i] = __float2bfloat16(je_w1[k * 256 + n]);
  }
  for (int i = tid; i < 256 * 256; i += stride) {
    int n = i >> 8, k = i & 255;
    Wj2[i] = __float2bfloat16(je_w2[k * 256 + n]);
  }
  for (int i = tid; i < 128 * 256; i += stride) {
    int n = i >> 8, k = i & 255;
    Wj3[i] = __float2bfloat16(je_w3[k * 128 + n]);
  }
  for (int i = tid; i < 4 * 384 * 128; i += stride) {
    int d = i / 49152, rem = i - d * 49152;
    int n = rem >> 7, k = rem & 127;
    Wq[i] = __float2bfloat16(qkv_w[d * 49152 + k * 384 + n]);
  }
  for (int i = tid; i < 4 * 128 * 128; i += stride) {
    int d = i >> 14, rem = i & 16383;
    int n = rem >> 7, k = rem & 127;
    Wp[i] = __float2bfloat16(proj_w[d * 16384 + k * 128 + n]);
    Wm1[i] = __float2bfloat16(mw1[d * 16384 + k * 128 + n]);
    Wm2[i] = __float2bfloat16(mw2[d * 16384 + k * 128 + n]);
  }
  for (int i = tid; i < 256 * 128; i += stride) {
    int n = i >> 7, k = i & 127;
    Wd1[i] = __float2bfloat16(dw1[k * 256 + n]);
  }
  for (int i = tid; i < 512 * 256; i += stride) {
    int n = i >> 8, k = i & 255;
    Wd2[i] = __float2bfloat16(dw2[k * 512 + n]);
  }
  for (int i = tid; i < 128 * 512; i += stride) {
    int n = i >> 9, k = i & 511;
    Wd3[i] = __float2bfloat16(n < 90 ? dw3[k * 90 + n] : 0.f);
  }
}

// ---- LayerNorm over last dim 128, bf16 out ----
__global__ void k_ln(const float* __restrict__ in, const float* __restrict__ g,
                     const float* __restrict__ b, bf16* __restrict__ out) {
  __shared__ float sred[8];
  int row = blockIdx.x;
  int t = threadIdx.x;
  float x = in[(long)row * 128 + t];
  float mean = blk_sum(x, sred) * (1.f / 128.f);
  float d = x - mean;
  float var = blk_sum(d * d, sred) * (1.f / 128.f);
  out[(long)row * 128 + t] = __float2bfloat16(d * rsqrtf(var + 1e-5f) * g[t] + b[t]);
}

// ---- fused attention for one depth: logits + conn + softmax + AV ----
__global__ void k_attn(const float* __restrict__ qkv, const bf16* __restrict__ aR,
                       const float* __restrict__ conn, bf16* __restrict__ obuf) {
  __shared__ float q[16];
  __shared__ float p[256];
  __shared__ float sred[8];
  __shared__ float pv[16][17];
  int n = blockIdx.x, h = blockIdx.y, b = blockIdx.z;
  int t = threadIdx.x;
  if (t < 16) q[t] = qkv[((long)(b * Nn + n)) * 384 + h * 16 + t];
  __syncthreads();
  const float* kp = &qkv[((long)(b * Nn + t)) * 384 + 128 + h * 16];
  float lg = 0.f;
#pragma unroll
  for (int e = 0; e < 16; ++e) lg += q[e] * kp[e];
  lg += toF(aR[(((long)(b * Hh + h) * Nn + n)) * Nn + t]);
  lg = lg * conn[((long)(b * Nn + n)) * Nn + t] * 0.25f;
  float mx = blk_max(lg, sred);
  float ex = expf(lg - mx);
  float s = blk_sum(ex, sred);
  p[t] = ex / s;
  __syncthreads();
  int g = t >> 4, e = t & 15;
  const float* vp = &qkv[((long)(b * Nn + g * 16)) * 384 + 256 + h * 16 + e];
  float acc = 0.f;
#pragma unroll
  for (int mi = 0; mi < 16; ++mi) acc += p[g * 16 + mi] * vp[(long)mi * 384];
  pv[g][e] = acc;
  __syncthreads();
  if (t < 16) {
    float s2 = 0.f;
#pragma unroll
    for (int gg = 0; gg < 16; ++gg) s2 += pv[gg][t];
    obuf[((long)(b * Nn + n)) * 128 + h * 16 + t] = __float2bfloat16(s2);
  }
}

extern "C" void kernel_launch(void* const* d_in, const int* in_sizes, int n_in,
                              void* d_out, int out_size, void* d_ws, size_t ws_size,
                              hipStream_t stream) {
  const float* joint_in = (const float*)d_in[0];
  const float* relation_in = (const float*)d_in[1];
  const float* conn = (const float*)d_in[2];
  const float* je_w1 = (const float*)d_in[3];
  const float* je_b1 = (const float*)d_in[4];
  const float* je_w2 = (const float*)d_in[5];
  const float* je_b2 = (const float*)d_in[6];
  const float* je_w3 = (const float*)d_in[7];
  const float* je_b3 = (const float*)d_in[8];
  const float* re_w1 = (const float*)d_in[9];
  const float* re_b1 = (const float*)d_in[10];
  const float* re_w2 = (const float*)d_in[11];
  const float* re_b2 = (const float*)d_in[12];
  const float* re_w3 = (const float*)d_in[13];
  const float* re_b3 = (const float*)d_in[14];
  const float* qkv_w = (const float*)d_in[15];
  const float* qkv_b = (const float*)d_in[16];
  const float* rconv_w = (const float*)d_in[17];
  const float* rconv_b = (const float*)d_in[18];
  const float* proj_w = (const float*)d_in[19];
  const float* proj_b = (const float*)d_in[20];
  const float* ln1_g = (const float*)d_in[21];
  const float* ln1_b = (const float*)d_in[22];
  const float* ln2_g = (const float*)d_in[23];
  const float* ln2_b = (const float*)d_in[24];
  const float* ln3_g = (const float*)d_in[25];
  const float* ln3_b = (const float*)d_in[26];
  const float* mw1 = (const float*)d_in[27];
  const float* mb1 = (const float*)d_in[28];
  const float* mw2 = (const float*)d_in[29];
  const float* mb2 = (const float*)d_in[30];
  const float* ng = (const float*)d_in[31];
  const float* nb = (const float*)d_in[32];
  const float* dw1 = (const float*)d_in[33];
  const float* db1 = (const float*)d_in[34];
  const float* dw2 = (const float*)d_in[35];
  const float* db2 = (const float*)d_in[36];
  const float* dw3 = (const float*)d_in[37];
  const float* db3 = (const float*)d_in[38];

  // ---- ws carve-up (~41.5 MiB) ----
  char* ws = (char*)d_ws;
  size_t off = 0;
  auto alloc = [&](size_t bytes) -> void* {
    void* p = ws + off;
    off += (bytes + 255) & ~(size_t)255;
    return p;
  };
  bf16* attnR = (bf16*)alloc((size_t)DEPTHd * Bb * Hh * Nn * Nn * 2);  // 33.55 MB
  bf16* Wt1 = (bf16*)alloc(256 * 32 * 2);
  bf16* Wt2 = (bf16*)alloc(256 * 256 * 2);
  bf16* Wt3 = (bf16*)alloc(128 * 256 * 2);
  bf16* gWt = (bf16*)alloc(32 * 128 * 2);
  float* sgW = (float*)alloc(32 * 4);
  float* bconst = (float*)alloc(32 * 4);
  bf16* Wj1 = (bf16*)alloc(256 * 96 * 2);
  bf16* Wj2 = (bf16*)alloc(256 * 256 * 2);
  bf16* Wj3 = (bf16*)alloc(128 * 256 * 2);
  bf16* Wq = (bf16*)alloc(4 * 384 * 128 * 2);
  bf16* Wp = (bf16*)alloc(4 * 128 * 128 * 2);
  bf16* Wm1 = (bf16*)alloc(4 * 128 * 128 * 2);
  bf16* Wm2 = (bf16*)alloc(4 * 128 * 128 * 2);
  bf16* Wd1 = (bf16*)alloc(256 * 128 * 2);
  bf16* Wd2 = (bf16*)alloc(512 * 256 * 2);
  bf16* Wd3 = (bf16*)alloc(128 * 512 * 2);
  float* jf = (float*)alloc((size_t)BN * 128 * 4);
  bf16* xb = (bf16*)alloc((size_t)BN * 128 * 2);
  bf16* obuf = (bf16*)alloc((size_t)BN * 128 * 2);
  bf16* hbuf = (bf16*)alloc((size_t)BN * 128 * 2);
  // union: qkvb (f32, transformer) | joint scratch / decoder scratch (bf16)
  char* U = (char*)alloc((size_t)BN * 384 * 4);  // 3.15 MB
  float* qkvb = (float*)U;
  bf16* u1 = (bf16*)U;                                 // BN*256 bf16
  bf16* u2 = (bf16*)(U + (size_t)BN * 256 * 2);        // BN*512 bf16

  // ---- prep all transposed bf16 weights ----
  k_prep<<<dim3(768), dim3(256), 0, stream>>>(
      re_w1, re_w2, re_w3, ln2_g, ln2_b, rconv_w, rconv_b, je_w1, je_w2, je_w3,
      qkv_w, proj_w, mw1, mw2, dw1, dw2, dw3, Wt1, Wt2, Wt3, gWt, sgW, bconst,
      Wj1, Wj2, Wj3, Wq, Wp, Wm1, Wm2, Wd1, Wd2, Wd3);

  // ---- joint encoder: 96 -> 256 -> 256 -> 128 (MFMA) ----
  k_gemm_mfma<float, bf16, false, false><<<dim3(2, 16), dim3(256), 0, stream>>>(
      joint_in, 96, 96, Wj1, je_b1, u1, 256, 256, nullptr);
  k_gemm_mfma<bf16, bf16, false, false><<<dim3(2, 16), dim3(256), 0, stream>>>(
      u1, 256, 256, Wj2, je_b2, u2, 256, 256, nullptr);
  k_gemm_mfma<bf16, float, false, false><<<dim3(1, 16), dim3(256), 0, stream>>>(
      u2, 256, 256, Wj3, je_b3, jf, 128, 128, nullptr);

  // ---- relation encoder fully fused -> attnR ----
  k_relfused<<<dim3(RTOT / 64), dim3(256), 0, stream>>>(
      relation_in, Wt1, re_b1, Wt2, re_b2, Wt3, re_b3, gWt, sgW, bconst, attnR);

  // ---- transformer blocks ----
  for (int d = 0; d < DEPTHd; ++d) {
    k_ln<<<dim3(BN), dim3(128), 0, stream>>>(jf, ln1_g + d * 128, ln1_b + d * 128, xb);
    k_gemm_mfma<bf16, float, false, false><<<dim3(3, 16), dim3(256), 0, stream>>>(
        xb, 128, 128, Wq + (size_t)d * 49152, qkv_b + d * 384, qkvb, 384, 384, nullptr);
    k_attn<<<dim3(Nn, Hh, Bb), dim3(256), 0, stream>>>(
        qkvb, attnR + (size_t)d * Bb * Hh * Nn * Nn, conn, obuf);
    k_gemm_mfma<bf16, float, false, true><<<dim3(1, 16), dim3(256), 0, stream>>>(
        obuf, 128, 128, Wp + (size_t)d * 16384, proj_b + d * 128, jf, 128, 128, jf);
    k_ln<<<dim3(BN), dim3(128), 0, stream>>>(jf, ln3_g + d * 128, ln3_b + d * 128, xb);
    k_gemm_mfma<bf16, bf16, true, false><<<dim3(1, 16), dim3(256), 0, stream>>>(
        xb, 128, 128, Wm1 + (size_t)d * 16384, mb1 + d * 128, hbuf, 128, 128, nullptr);
    k_gemm_mfma<bf16, float, false, true><<<dim3(1, 16), dim3(256), 0, stream>>>(
        hbuf, 128, 128, Wm2 + (size_t)d * 16384, mb2 + d * 128, jf, 128, 128, jf);
  }

  // ---- final LN + decoder 128 -> 256 -> 512 -> 90 (MFMA) ----
  k_ln<<<dim3(BN), dim3(128), 0, stream>>>(jf, ng, nb, xb);
  k_gemm_mfma<bf16, bf16, false, false><<<dim3(2, 16), dim3(256), 0, stream>>>(
      xb, 128, 128, Wd1, db1, u1, 256, 256, nullptr);
  k_gemm_mfma<bf16, bf16, false, false><<<dim3(4, 16), dim3(256), 0, stream>>>(
      u1, 256, 256, Wd2, db2, u2, 512, 512, nullptr);
  k_gemm_mfma<bf16, float, false, false><<<dim3(1, 16), dim3(256), 0, stream>>>(
      u2, 512, 512, Wd3, db3, (float*)d_out, 90, 90, nullptr);
}

// Round 7
// 1018.408 us; speedup vs baseline: 5.3487x; 1.1304x over previous
//
#include <hip/hip_runtime.h>
#include <hip/hip_bf16.h>
#include <math.h>

typedef __hip_bfloat16 bf16;
typedef __attribute__((ext_vector_type(8))) short short8;
typedef __attribute__((ext_vector_type(4))) float f32x4;

#define Bb 8
#define Nn 256
#define Hh 8
#define DEPTHd 4
#define BN 2048
#define RTOT 524288
#define X1S 264
#define X3S 136
#define XTS 136

__device__ inline float toF(float v) { return v; }
__device__ inline float toF(bf16 v) { return __bfloat162float(v); }
__device__ inline void stF(float* p, float v) { *p = v; }
__device__ inline void stF(bf16* p, float v) { *p = __float2bfloat16(v); }

__device__ inline void gload16(const bf16* g, bf16* l) {
  __builtin_amdgcn_global_load_lds(
      (const __attribute__((address_space(1))) unsigned int*)g,
      (__attribute__((address_space(3))) unsigned int*)l, 16, 0, 0);
}

__device__ inline float blk_sum(float v, float* sred) {
#pragma unroll
  for (int off = 32; off; off >>= 1) v += __shfl_down(v, off, 64);
  int wid = threadIdx.x >> 6;
  int lane = threadIdx.x & 63;
  int nw = blockDim.x >> 6;
  if (lane == 0) sred[wid] = v;
  __syncthreads();
  float s = ((int)threadIdx.x < nw) ? sred[threadIdx.x] : 0.f;
  s += __shfl_down(s, 2, 64);
  s += __shfl_down(s, 1, 64);
  if (threadIdx.x == 0) sred[4] = s;
  __syncthreads();
  float r = sred[4];
  __syncthreads();
  return r;
}

__device__ inline float blk_max(float v, float* sred) {
#pragma unroll
  for (int off = 32; off; off >>= 1) v = fmaxf(v, __shfl_down(v, off, 64));
  int wid = threadIdx.x >> 6;
  int lane = threadIdx.x & 63;
  int nw = blockDim.x >> 6;
  if (lane == 0) sred[wid] = v;
  __syncthreads();
  float s = ((int)threadIdx.x < nw) ? sred[threadIdx.x] : -INFINITY;
  s = fmaxf(s, __shfl_down(s, 2, 64));
  s = fmaxf(s, __shfl_down(s, 1, 64));
  if (threadIdx.x == 0) sred[4] = s;
  __syncthreads();
  float r = sred[4];
  __syncthreads();
  return r;
}

// =============== MFMA GEMM (generic, LDS-staged): joint enc + decoder 2/3 ===============
template <typename TA, typename TC, bool GELU, bool RESID>
__global__ __launch_bounds__(256) void k_gemm_mfma(
    const TA* __restrict__ A, int Ka, int Kp, const bf16* __restrict__ Bt,
    const float* __restrict__ bias, TC* __restrict__ C, int ldc, int ncols,
    const float* __restrict__ resid) {
  __shared__ __align__(16) bf16 sA[128 * 32];
  __shared__ __align__(16) bf16 sB[128 * 32];
  const int t = threadIdx.x;
  const int lane = t & 63;
  const int wv = t >> 6;
  const int wr = wv >> 1, wc = wv & 1;
  const int lrow = lane & 15, quad = lane >> 4;
  const long row0 = (long)blockIdx.y * 128;
  const int n0 = blockIdx.x * 128;
  const int rg = lane >> 2;
  const int kE = (lane & 3) * 8;

  f32x4 zero = {0.f, 0.f, 0.f, 0.f};
  f32x4 acc[4][4];
#pragma unroll
  for (int i = 0; i < 4; ++i)
#pragma unroll
    for (int j = 0; j < 4; ++j) acc[i][j] = zero;

  for (int k0 = 0; k0 < Kp; k0 += 32) {
    {
      const int r0 = wv * 32;
      gload16(&Bt[(long)(n0 + r0 + rg) * Kp + k0 + kE], &sB[r0 * 32]);
      gload16(&Bt[(long)(n0 + r0 + 16 + rg) * Kp + k0 + kE], &sB[(r0 + 16) * 32]);
    }
    if (sizeof(TA) == 2) {
      const int r0 = wv * 32;
      gload16((const bf16*)&A[(row0 + r0 + rg) * (long)Ka + k0 + kE], &sA[r0 * 32]);
      gload16((const bf16*)&A[(row0 + r0 + 16 + rg) * (long)Ka + k0 + kE],
              &sA[(r0 + 16) * 32]);
    } else {
      for (int idx = t; idx < 128 * 32; idx += 256) {
        int r = idx >> 5, k = idx & 31;
        int gk = k0 + k;
        float v = (gk < Ka) ? toF(A[(row0 + r) * (long)Ka + gk]) : 0.f;
        sA[idx] = __float2bfloat16(v);
      }
    }
    __syncthreads();
    short8 af[4], bfr[4];
#pragma unroll
    for (int i = 0; i < 4; ++i)
      af[i] = *(const short8*)&sA[(wr * 64 + i * 16 + lrow) * 32 + quad * 8];
#pragma unroll
    for (int j = 0; j < 4; ++j)
      bfr[j] = *(const short8*)&sB[(wc * 64 + j * 16 + lrow) * 32 + quad * 8];
#pragma unroll
    for (int i = 0; i < 4; ++i)
#pragma unroll
      for (int j = 0; j < 4; ++j)
        acc[i][j] =
            __builtin_amdgcn_mfma_f32_16x16x32_bf16(af[i], bfr[j], acc[i][j], 0, 0, 0);
    __syncthreads();
  }

#pragma unroll
  for (int i = 0; i < 4; ++i) {
#pragma unroll
    for (int r = 0; r < 4; ++r) {
      int rl = wr * 64 + i * 16 + quad * 4 + r;
      long gr = row0 + rl;
#pragma unroll
      for (int j = 0; j < 4; ++j) {
        int gc = n0 + wc * 64 + j * 16 + lrow;
        if (gc < ncols) {
          float v = acc[i][j][r] + bias[gc];
          if (GELU) v = 0.5f * v * (1.f + erff(v * 0.70710678118654752f));
          if (RESID) v += resid[gr * (long)ldc + gc];
          stF(&C[gr * (long)ldc + gc], v);
        }
      }
    }
  }
}

// =============== fused relation encoder + LN2 + rconv -> attnR (prefetched) ===============
__global__ __launch_bounds__(256) void k_relfused(
    const float* __restrict__ rin, const bf16* __restrict__ Wt1,
    const float* __restrict__ b1, const bf16* __restrict__ Wt2,
    const float* __restrict__ b2, const bf16* __restrict__ Wt3,
    const float* __restrict__ b3, const bf16* __restrict__ gWt,
    const float* __restrict__ sgW, const float* __restrict__ bconst,
    bf16* __restrict__ attnR) {
  __shared__ __align__(16) char smem[67584];
  bf16* x1 = (bf16*)smem;                     // [64][264]
  bf16* x2 = (bf16*)(smem + 33792);           // [64][264]
  bf16* x3 = x1;                              // [64][136]
  float* sstat = (float*)(smem + 18432);
  float* sstatF = (float*)(smem + 20480);
  bf16* sA0 = x2;                             // [64][32] staging

  const int t = threadIdx.x;
  const int lane = t & 63, wv = t >> 6;
  const int lrow = lane & 15, quad = lane >> 4;
  const long r0 = (long)blockIdx.x * 64;

  // hoist L1 weights (independent of LDS) to overlap with staging
  short8 bw1[4];
#pragma unroll
  for (int j = 0; j < 4; ++j)
    bw1[j] = *(const short8*)&Wt1[(wv * 64 + j * 16 + lrow) * 32 + quad * 8];

  for (int idx = t; idx < 64 * 32; idx += 256) {
    int r = idx >> 5, k = idx & 31;
    sA0[idx] = __float2bfloat16(k < 26 ? rin[(r0 + r) * 26 + k] : 0.f);
  }
  __syncthreads();

  // ---- L1: x1 = A0 @ Wt1^T + b1 (K=32) ----
  {
    short8 af[4];
#pragma unroll
    for (int i = 0; i < 4; ++i)
      af[i] = *(const short8*)&sA0[(i * 16 + lrow) * 32 + quad * 8];
    f32x4 acc[4][4];
#pragma unroll
    for (int i = 0; i < 4; ++i)
#pragma unroll
      for (int j = 0; j < 4; ++j) {
        f32x4 z = {0.f, 0.f, 0.f, 0.f};
        acc[i][j] = __builtin_amdgcn_mfma_f32_16x16x32_bf16(af[i], bw1[j], z, 0, 0, 0);
      }
#pragma unroll
    for (int i = 0; i < 4; ++i)
#pragma unroll
      for (int j = 0; j < 4; ++j) {
        int col = wv * 64 + j * 16 + lrow;
        float bv = b1[col];
#pragma unroll
        for (int r = 0; r < 4; ++r) {
          int row = i * 16 + quad * 4 + r;
          x1[row * X1S + col] = __float2bfloat16(acc[i][j][r] + bv);
        }
      }
  }
  __syncthreads();

  // ---- L2: x2 = x1 @ Wt2^T + b2 (K=256), depth-1 prefetch ----
  {
    f32x4 acc[4][4];
#pragma unroll
    for (int i = 0; i < 4; ++i)
#pragma unroll
      for (int j = 0; j < 4; ++j) {
        f32x4 z = {0.f, 0.f, 0.f, 0.f};
        acc[i][j] = z;
      }
    short8 bn[4], an[4];
#pragma unroll
    for (int j = 0; j < 4; ++j)
      bn[j] = *(const short8*)&Wt2[(wv * 64 + j * 16 + lrow) * 256 + quad * 8];
#pragma unroll
    for (int i = 0; i < 4; ++i)
      an[i] = *(const short8*)&x1[(i * 16 + lrow) * X1S + quad * 8];
#pragma unroll
    for (int k0 = 0; k0 < 256; k0 += 32) {
      short8 bc[4], ac[4];
#pragma unroll
      for (int j = 0; j < 4; ++j) bc[j] = bn[j];
#pragma unroll
      for (int i = 0; i < 4; ++i) ac[i] = an[i];
      if (k0 + 32 < 256) {
#pragma unroll
        for (int j = 0; j < 4; ++j)
          bn[j] = *(const short8*)&Wt2[(wv * 64 + j * 16 + lrow) * 256 + k0 + 32 +
                                       quad * 8];
#pragma unroll
        for (int i = 0; i < 4; ++i)
          an[i] = *(const short8*)&x1[(i * 16 + lrow) * X1S + k0 + 32 + quad * 8];
      }
#pragma unroll
      for (int i = 0; i < 4; ++i)
#pragma unroll
        for (int j = 0; j < 4; ++j)
          acc[i][j] =
              __builtin_amdgcn_mfma_f32_16x16x32_bf16(ac[i], bc[j], acc[i][j], 0, 0, 0);
    }
#pragma unroll
    for (int i = 0; i < 4; ++i)
#pragma unroll
      for (int j = 0; j < 4; ++j) {
        int col = wv * 64 + j * 16 + lrow;
        float bv = b2[col];
#pragma unroll
        for (int r = 0; r < 4; ++r) {
          int row = i * 16 + quad * 4 + r;
          x2[row * X1S + col] = __float2bfloat16(acc[i][j][r] + bv);
        }
      }
  }
  __syncthreads();

  // ---- L3: x3 = x2 @ Wt3^T + b3 (K=256) + LN stats, prefetch ----
  {
    f32x4 acc[4][2];
#pragma unroll
    for (int i = 0; i < 4; ++i) {
      f32x4 z = {0.f, 0.f, 0.f, 0.f};
      acc[i][0] = z;
      acc[i][1] = z;
    }
    short8 bn[2], an[4];
#pragma unroll
    for (int j = 0; j < 2; ++j)
      bn[j] = *(const short8*)&Wt3[(wv * 32 + j * 16 + lrow) * 256 + quad * 8];
#pragma unroll
    for (int i = 0; i < 4; ++i)
      an[i] = *(const short8*)&x2[(i * 16 + lrow) * X1S + quad * 8];
#pragma unroll
    for (int k0 = 0; k0 < 256; k0 += 32) {
      short8 bc[2], ac[4];
      bc[0] = bn[0];
      bc[1] = bn[1];
#pragma unroll
      for (int i = 0; i < 4; ++i) ac[i] = an[i];
      if (k0 + 32 < 256) {
#pragma unroll
        for (int j = 0; j < 2; ++j)
          bn[j] = *(const short8*)&Wt3[(wv * 32 + j * 16 + lrow) * 256 + k0 + 32 +
                                       quad * 8];
#pragma unroll
        for (int i = 0; i < 4; ++i)
          an[i] = *(const short8*)&x2[(i * 16 + lrow) * X1S + k0 + 32 + quad * 8];
      }
#pragma unroll
      for (int i = 0; i < 4; ++i)
#pragma unroll
        for (int j = 0; j < 2; ++j)
          acc[i][j] =
              __builtin_amdgcn_mfma_f32_16x16x32_bf16(ac[i], bc[j], acc[i][j], 0, 0, 0);
    }
#pragma unroll
    for (int i = 0; i < 4; ++i) {
#pragma unroll
      for (int r = 0; r < 4; ++r) {
        int row = i * 16 + quad * 4 + r;
        float v0 = acc[i][0][r] + b3[wv * 32 + lrow];
        float v1 = acc[i][1][r] + b3[wv * 32 + 16 + lrow];
        x3[row * X3S + wv * 32 + lrow] = __float2bfloat16(v0);
        x3[row * X3S + wv * 32 + 16 + lrow] = __float2bfloat16(v1);
        float s1 = v0 + v1, s2 = v0 * v0 + v1 * v1;
#pragma unroll
        for (int m = 1; m < 16; m <<= 1) {
          s1 += __shfl_xor(s1, m, 64);
          s2 += __shfl_xor(s2, m, 64);
        }
        if (lrow == 0) {
          sstat[(row * 4 + wv) * 2] = s1;
          sstat[(row * 4 + wv) * 2 + 1] = s2;
        }
      }
    }
  }
  // hoist gemm32 A-operands (global gWt) to overlap with stats barriers
  short8 aw0[4], aw1[4];
#pragma unroll
  for (int kk = 0; kk < 4; ++kk) {
    aw0[kk] = *(const short8*)&gWt[lrow * 128 + kk * 32 + quad * 8];
    aw1[kk] = *(const short8*)&gWt[(16 + lrow) * 128 + kk * 32 + quad * 8];
  }
  __syncthreads();
  if (t < 64) {
    float s1 = 0.f, s2 = 0.f;
#pragma unroll
    for (int w = 0; w < 4; ++w) {
      s1 += sstat[(t * 4 + w) * 2];
      s2 += sstat[(t * 4 + w) * 2 + 1];
    }
    float mu = s1 * (1.f / 128.f);
    float var = s2 * (1.f / 128.f) - mu * mu;
    sstatF[t * 2] = mu;
    sstatF[t * 2 + 1] = rsqrtf(var + 1e-5f);
  }
  __syncthreads();

  // ---- gemm32: gW @ x3^T, LN stats trick, scatter ----
  {
    f32x4 acc2[2];
    {
      f32x4 z = {0.f, 0.f, 0.f, 0.f};
      acc2[0] = z;
      acc2[1] = z;
    }
#pragma unroll
    for (int kk = 0; kk < 4; ++kk) {
      short8 bb = *(const short8*)&x3[(wv * 16 + lrow) * X3S + kk * 32 + quad * 8];
      acc2[0] = __builtin_amdgcn_mfma_f32_16x16x32_bf16(aw0[kk], bb, acc2[0], 0, 0, 0);
      acc2[1] = __builtin_amdgcn_mfma_f32_16x16x32_bf16(aw1[kk], bb, acc2[1], 0, 0, 0);
    }
    int drow = wv * 16 + lrow;
    long gr = r0 + drow;
    float mu = sstatF[drow * 2], inv = sstatF[drow * 2 + 1];
    int bb_ = (int)(gr >> 16);
    int nn = (int)((gr >> 8) & 255);
    int mm = (int)(gr & 255);
#pragma unroll
    for (int mt = 0; mt < 2; ++mt) {
#pragma unroll
      for (int reg = 0; reg < 4; ++reg) {
        int col = mt * 16 + quad * 4 + reg;
        float v = inv * (acc2[mt][reg] - mu * sgW[col]) + bconst[col];
        int dd = col >> 3, hh = col & 7;
        attnR[((((long)dd * Bb + bb_) * Hh + hh) * Nn + nn) * Nn + mm] =
            __float2bfloat16(v);
      }
    }
  }
}

// =============== k_lnqkv: row-LN (dim 128) fused into K=128 GEMM ===============
// A f32 [rows][128]; out C[rows][ncols] = LN(A) @ Bt^T + bias. grid (colTiles, rowTiles)
template <typename TC>
__global__ __launch_bounds__(256) void k_lnqkv(
    const float* __restrict__ A, const float* __restrict__ g,
    const float* __restrict__ b, const bf16* __restrict__ Bt,
    const float* __restrict__ bias, TC* __restrict__ C, int ldc, int ncols) {
  __shared__ __align__(16) bf16 sX[128 * XTS];
  const int t = threadIdx.x;
  const int lane = t & 63;
  const int wv = t >> 6;
  const int wr = wv >> 1, wc = wv & 1;
  const int lrow = lane & 15, quad = lane >> 4;
  const long row0 = (long)blockIdx.y * 128;
  const int n0 = blockIdx.x * 128;

  // stage + LN: 2 threads per row
  {
    int row = t >> 1, half = t & 1;
    const float* ap = &A[(row0 + row) * 128 + half * 64];
    float v[64];
    float s1 = 0.f, s2 = 0.f;
#pragma unroll
    for (int u = 0; u < 16; ++u) {
      f32x4 q = *(const f32x4*)(ap + u * 4);
#pragma unroll
      for (int e = 0; e < 4; ++e) {
        v[u * 4 + e] = q[e];
        s1 += q[e];
        s2 += q[e] * q[e];
      }
    }
    s1 += __shfl_xor(s1, 1, 64);
    s2 += __shfl_xor(s2, 1, 64);
    float mu = s1 * (1.f / 128.f);
    float inv = rsqrtf(s2 * (1.f / 128.f) - mu * mu + 1e-5f);
#pragma unroll
    for (int u = 0; u < 64; ++u) {
      int c = half * 64 + u;
      sX[row * XTS + c] = __float2bfloat16((v[u] - mu) * inv * g[c] + b[c]);
    }
  }
  __syncthreads();

  f32x4 acc[4][4];
#pragma unroll
  for (int i = 0; i < 4; ++i)
#pragma unroll
    for (int j = 0; j < 4; ++j) {
      f32x4 z = {0.f, 0.f, 0.f, 0.f};
      acc[i][j] = z;
    }
  short8 bn[4], an[4];
#pragma unroll
  for (int j = 0; j < 4; ++j)
    bn[j] = *(const short8*)&Bt[(long)(n0 + wc * 64 + j * 16 + lrow) * 128 + quad * 8];
#pragma unroll
  for (int i = 0; i < 4; ++i)
    an[i] = *(const short8*)&sX[(wr * 64 + i * 16 + lrow) * XTS + quad * 8];
#pragma unroll
  for (int k0 = 0; k0 < 128; k0 += 32) {
    short8 bc[4], ac[4];
#pragma unroll
    for (int j = 0; j < 4; ++j) bc[j] = bn[j];
#pragma unroll
    for (int i = 0; i < 4; ++i) ac[i] = an[i];
    if (k0 + 32 < 128) {
#pragma unroll
      for (int j = 0; j < 4; ++j)
        bn[j] = *(const short8*)&Bt[(long)(n0 + wc * 64 + j * 16 + lrow) * 128 + k0 +
                                    32 + quad * 8];
#pragma unroll
      for (int i = 0; i < 4; ++i)
        an[i] = *(const short8*)&sX[(wr * 64 + i * 16 + lrow) * XTS + k0 + 32 + quad * 8];
    }
#pragma unroll
    for (int i = 0; i < 4; ++i)
#pragma unroll
      for (int j = 0; j < 4; ++j)
        acc[i][j] =
            __builtin_amdgcn_mfma_f32_16x16x32_bf16(ac[i], bc[j], acc[i][j], 0, 0, 0);
  }
#pragma unroll
  for (int i = 0; i < 4; ++i) {
#pragma unroll
    for (int r = 0; r < 4; ++r) {
      long gr = row0 + wr * 64 + i * 16 + quad * 4 + r;
#pragma unroll
      for (int j = 0; j < 4; ++j) {
        int gc = n0 + wc * 64 + j * 16 + lrow;
        if (gc < ncols) stF(&C[gr * (long)ldc + gc], acc[i][j][r] + bias[gc]);
      }
    }
  }
}

// =============== k_tail: jf += proj(o); x=LN3(jf); h=gelu(x@Wm1); jf += h@Wm2 ===============
// grid = 16 blocks x 128 rows, 256 thr (4 waves 2x2).
__global__ __launch_bounds__(256) void k_tail(
    const bf16* __restrict__ obuf, float* __restrict__ jf, const bf16* __restrict__ Wp,
    const float* __restrict__ pb, const float* __restrict__ g3,
    const float* __restrict__ b3, const bf16* __restrict__ Wm1,
    const float* __restrict__ m1b, const bf16* __restrict__ Wm2,
    const float* __restrict__ m2b) {
  __shared__ __align__(16) bf16 sX[128 * XTS];
  __shared__ __align__(16) bf16 sH[128 * XTS];
  __shared__ float sstat[128][2][2];
  __shared__ float sstatF[128][2];

  const int t = threadIdx.x;
  const int lane = t & 63;
  const int wv = t >> 6;
  const int wr = wv >> 1, wc = wv & 1;
  const int lrow = lane & 15, quad = lane >> 4;
  const long row0 = (long)blockIdx.x * 128;

  // stage obuf tile into sX
#pragma unroll
  for (int u = 0; u < 8; ++u) {
    int idx = t + u * 256;
    int r = idx >> 4, c8 = (idx & 15) * 8;
    *(uint4*)&sX[r * XTS + c8] = *(const uint4*)&obuf[(row0 + r) * 128 + c8];
  }
  __syncthreads();

  f32x4 acc[4][4];
#pragma unroll
  for (int i = 0; i < 4; ++i)
#pragma unroll
    for (int j = 0; j < 4; ++j) {
      f32x4 z = {0.f, 0.f, 0.f, 0.f};
      acc[i][j] = z;
    }
  // GEMM1: proj
#pragma unroll
  for (int k0 = 0; k0 < 128; k0 += 32) {
    short8 af[4], bfr[4];
#pragma unroll
    for (int i = 0; i < 4; ++i)
      af[i] = *(const short8*)&sX[(wr * 64 + i * 16 + lrow) * XTS + k0 + quad * 8];
#pragma unroll
    for (int j = 0; j < 4; ++j)
      bfr[j] = *(const short8*)&Wp[(wc * 64 + j * 16 + lrow) * 128 + k0 + quad * 8];
#pragma unroll
    for (int i = 0; i < 4; ++i)
#pragma unroll
      for (int j = 0; j < 4; ++j)
        acc[i][j] =
            __builtin_amdgcn_mfma_f32_16x16x32_bf16(af[i], bfr[j], acc[i][j], 0, 0, 0);
  }
  // epilogue: jf_new = acc + pb + jf_old; store jf; stats
#pragma unroll
  for (int i = 0; i < 4; ++i) {
#pragma unroll
    for (int r = 0; r < 4; ++r) {
      int rl = wr * 64 + i * 16 + quad * 4 + r;
      long gr = row0 + rl;
      float s1 = 0.f, s2 = 0.f;
#pragma unroll
      for (int j = 0; j < 4; ++j) {
        int gc = wc * 64 + j * 16 + lrow;
        float v = acc[i][j][r] + pb[gc] + jf[gr * 128 + gc];
        acc[i][j][r] = v;
        jf[gr * 128 + gc] = v;
        s1 += v;
        s2 += v * v;
      }
#pragma unroll
      for (int m = 1; m < 16; m <<= 1) {
        s1 += __shfl_xor(s1, m, 64);
        s2 += __shfl_xor(s2, m, 64);
      }
      if (lrow == 0) {
        sstat[rl][wc][0] = s1;
        sstat[rl][wc][1] = s2;
      }
    }
  }
  __syncthreads();
  if (t < 128) {
    float s1 = sstat[t][0][0] + sstat[t][1][0];
    float s2 = sstat[t][0][1] + sstat[t][1][1];
    float mu = s1 * (1.f / 128.f);
    float var = s2 * (1.f / 128.f) - mu * mu;
    sstatF[t][0] = mu;
    sstatF[t][1] = rsqrtf(var + 1e-5f);
  }
  __syncthreads();
  // x = LN3(jf_new) -> sX (A-tile dead: all waves past barrier)
#pragma unroll
  for (int i = 0; i < 4; ++i) {
#pragma unroll
    for (int r = 0; r < 4; ++r) {
      int rl = wr * 64 + i * 16 + quad * 4 + r;
      float mu = sstatF[rl][0], inv = sstatF[rl][1];
#pragma unroll
      for (int j = 0; j < 4; ++j) {
        int gc = wc * 64 + j * 16 + lrow;
        sX[rl * XTS + gc] =
            __float2bfloat16((acc[i][j][r] - mu) * inv * g3[gc] + b3[gc]);
      }
    }
  }
  __syncthreads();

  // GEMM2: h = gelu(x @ Wm1 + m1b) -> sH
  f32x4 acc2[4][4];
#pragma unroll
  for (int i = 0; i < 4; ++i)
#pragma unroll
    for (int j = 0; j < 4; ++j) {
      f32x4 z = {0.f, 0.f, 0.f, 0.f};
      acc2[i][j] = z;
    }
#pragma unroll
  for (int k0 = 0; k0 < 128; k0 += 32) {
    short8 af[4], bfr[4];
#pragma unroll
    for (int i = 0; i < 4; ++i)
      af[i] = *(const short8*)&sX[(wr * 64 + i * 16 + lrow) * XTS + k0 + quad * 8];
#pragma unroll
    for (int j = 0; j < 4; ++j)
      bfr[j] = *(const short8*)&Wm1[(wc * 64 + j * 16 + lrow) * 128 + k0 + quad * 8];
#pragma unroll
    for (int i = 0; i < 4; ++i)
#pragma unroll
      for (int j = 0; j < 4; ++j)
        acc2[i][j] =
            __builtin_amdgcn_mfma_f32_16x16x32_bf16(af[i], bfr[j], acc2[i][j], 0, 0, 0);
  }
#pragma unroll
  for (int i = 0; i < 4; ++i) {
#pragma unroll
    for (int r = 0; r < 4; ++r) {
      int rl = wr * 64 + i * 16 + quad * 4 + r;
#pragma unroll
      for (int j = 0; j < 4; ++j) {
        int gc = wc * 64 + j * 16 + lrow;
        float v = acc2[i][j][r] + m1b[gc];
        v = 0.5f * v * (1.f + erff(v * 0.70710678118654752f));
        sH[rl * XTS + gc] = __float2bfloat16(v);
      }
    }
  }
  __syncthreads();

  // GEMM3: jf = h @ Wm2 + m2b + jf_new
  f32x4 acc3[4][4];
#pragma unroll
  for (int i = 0; i < 4; ++i)
#pragma unroll
    for (int j = 0; j < 4; ++j) {
      f32x4 z = {0.f, 0.f, 0.f, 0.f};
      acc3[i][j] = z;
    }
#pragma unroll
  for (int k0 = 0; k0 < 128; k0 += 32) {
    short8 af[4], bfr[4];
#pragma unroll
    for (int i = 0; i < 4; ++i)
      af[i] = *(const short8*)&sH[(wr * 64 + i * 16 + lrow) * XTS + k0 + quad * 8];
#pragma unroll
    for (int j = 0; j < 4; ++j)
      bfr[j] = *(const short8*)&Wm2[(wc * 64 + j * 16 + lrow) * 128 + k0 + quad * 8];
#pragma unroll
    for (int i = 0; i < 4; ++i)
#pragma unroll
      for (int j = 0; j < 4; ++j)
        acc3[i][j] =
            __builtin_amdgcn_mfma_f32_16x16x32_bf16(af[i], bfr[j], acc3[i][j], 0, 0, 0);
  }
#pragma unroll
  for (int i = 0; i < 4; ++i) {
#pragma unroll
    for (int r = 0; r < 4; ++r) {
      int rl = wr * 64 + i * 16 + quad * 4 + r;
      long gr = row0 + rl;
#pragma unroll
      for (int j = 0; j < 4; ++j) {
        int gc = wc * 64 + j * 16 + lrow;
        jf[gr * 128 + gc] = acc3[i][j][r] + m2b[gc] + jf[gr * 128 + gc];
      }
    }
  }
}

// ---- prep: transpose+cast all weights to bf16 [col][K]; build gW / sgW / bconst ----
__global__ void k_prep(const float* re_w1, const float* re_w2, const float* re_w3,
                       const float* ln2_g, const float* ln2_b, const float* rconv_w,
                       const float* rconv_b, const float* je_w1, const float* je_w2,
                       const float* je_w3, const float* qkv_w, const float* proj_w,
                       const float* mw1, const float* mw2, const float* dw1,
                       const float* dw2, const float* dw3, bf16* Wt1, bf16* Wt2,
                       bf16* Wt3, bf16* gWt, float* sgW, float* bconst, bf16* Wj1,
                       bf16* Wj2, bf16* Wj3, bf16* Wq, bf16* Wp, bf16* Wm1, bf16* Wm2,
                       bf16* Wd1, bf16* Wd2, bf16* Wd3) {
  const int stride = gridDim.x * blockDim.x;
  const int tid = blockIdx.x * blockDim.x + threadIdx.x;
  for (int i = tid; i < 256 * 32; i += stride) {
    int n = i >> 5, k = i & 31;
    Wt1[i] = __float2bfloat16(k < 26 ? re_w1[k * 256 + n] : 0.f);
  }
  for (int i = tid; i < 256 * 256; i += stride) {
    int n = i >> 8, k = i & 255;
    Wt2[i] = __float2bfloat16(re_w2[k * 256 + n]);
  }
  for (int i = tid; i < 128 * 256; i += stride) {
    int n = i >> 8, k = i & 255;
    Wt3[i] = __float2bfloat16(re_w3[k * 128 + n]);
  }
  for (int i = tid; i < 32 * 128; i += stride) {
    int col = i >> 7, c = i & 127;
    int dd = col >> 3, h = col & 7;
    gWt[i] = __float2bfloat16(ln2_g[dd * 128 + c] * rconv_w[(dd * 128 + c) * 8 + h]);
  }
  if (tid < 32) {
    int dd = tid >> 3, h = tid & 7;
    float sg = 0.f, bc = 0.f;
    for (int c = 0; c < 128; ++c) {
      float w = rconv_w[(dd * 128 + c) * 8 + h];
      sg += ln2_g[dd * 128 + c] * w;
      bc += ln2_b[dd * 128 + c] * w;
    }
    sgW[tid] = sg;
    bconst[tid] = bc + rconv_b[tid];
  }
  for (int i = tid; i < 256 * 96; i += stride) {
    int n = i / 96, k = i - n * 96;
    Wj1[i] = __float2bfloat16(je_w1[k * 256 + n]);
  }
  for (int i = tid; i < 256 * 256; i += stride) {
    int n = i >> 8, k = i & 255;
    Wj2[i] = __float2bfloat16(je_w2[k * 256 + n]);
  }
  for (int i = tid; i < 128 * 256; i += stride) {
    int n = i >> 8, k = i & 255;
    Wj3[i] = __float2bfloat16(je_w3[k * 128 + n]);
  }
  for (int i = tid; i < 4 * 384 * 128; i += stride) {
    int d = i / 49152, rem = i - d * 49152;
    int n = rem >> 7, k = rem & 127;
    Wq[i] = __float2bfloat16(qkv_w[d * 49152 + k * 384 + n]);
  }
  for (int i = tid; i < 4 * 128 * 128; i += stride) {
    int d = i >> 14, rem = i & 16383;
    int n = rem >> 7, k = rem & 127;
    Wp[i] = __float2bfloat16(proj_w[d * 16384 + k * 128 + n]);
    Wm1[i] = __float2bfloat16(mw1[d * 16384 + k * 128 + n]);
    Wm2[i] = __float2bfloat16(mw2[d * 16384 + k * 128 + n]);
  }
  for (int i = tid; i < 256 * 128; i += stride) {
    int n = i >> 7, k = i & 127;
    Wd1[i] = __float2bfloat16(dw1[k * 256 + n]);
  }
  for (int i = tid; i < 512 * 256; i += stride) {
    int n = i >> 8, k = i & 255;
    Wd2[i] = __float2bfloat16(dw2[k * 512 + n]);
  }
  for (int i = tid; i < 128 * 512; i += stride) {
    int n = i >> 9, k = i & 511;
    Wd3[i] = __float2bfloat16(n < 90 ? dw3[k * 90 + n] : 0.f);
  }
}

// ---- fused attention: logits + conn + softmax + AV ----
__global__ void k_attn(const float* __restrict__ qkv, const bf16* __restrict__ aR,
                       const float* __restrict__ conn, bf16* __restrict__ obuf) {
  __shared__ float q[16];
  __shared__ float p[256];
  __shared__ float sred[8];
  __shared__ float pv[16][17];
  int n = blockIdx.x, h = blockIdx.y, b = blockIdx.z;
  int t = threadIdx.x;
  if (t < 16) q[t] = qkv[((long)(b * Nn + n)) * 384 + h * 16 + t];
  __syncthreads();
  const float* kp = &qkv[((long)(b * Nn + t)) * 384 + 128 + h * 16];
  float lg = 0.f;
#pragma unroll
  for (int e = 0; e < 16; ++e) lg += q[e] * kp[e];
  lg += toF(aR[(((long)(b * Hh + h) * Nn + n)) * Nn + t]);
  lg = lg * conn[((long)(b * Nn + n)) * Nn + t] * 0.25f;
  float mx = blk_max(lg, sred);
  float ex = expf(lg - mx);
  float s = blk_sum(ex, sred);
  p[t] = ex / s;
  __syncthreads();
  int g = t >> 4, e = t & 15;
  const float* vp = &qkv[((long)(b * Nn + g * 16)) * 384 + 256 + h * 16 + e];
  float acc = 0.f;
#pragma unroll
  for (int mi = 0; mi < 16; ++mi) acc += p[g * 16 + mi] * vp[(long)mi * 384];
  pv[g][e] = acc;
  __syncthreads();
  if (t < 16) {
    float s2 = 0.f;
#pragma unroll
    for (int gg = 0; gg < 16; ++gg) s2 += pv[gg][t];
    obuf[((long)(b * Nn + n)) * 128 + h * 16 + t] = __float2bfloat16(s2);
  }
}

extern "C" void kernel_launch(void* const* d_in, const int* in_sizes, int n_in,
                              void* d_out, int out_size, void* d_ws, size_t ws_size,
                              hipStream_t stream) {
  const float* joint_in = (const float*)d_in[0];
  const float* relation_in = (const float*)d_in[1];
  const float* conn = (const float*)d_in[2];
  const float* je_w1 = (const float*)d_in[3];
  const float* je_b1 = (const float*)d_in[4];
  const float* je_w2 = (const float*)d_in[5];
  const float* je_b2 = (const float*)d_in[6];
  const float* je_w3 = (const float*)d_in[7];
  const float* je_b3 = (const float*)d_in[8];
  const float* re_w1 = (const float*)d_in[9];
  const float* re_b1 = (const float*)d_in[10];
  const float* re_w2 = (const float*)d_in[11];
  const float* re_b2 = (const float*)d_in[12];
  const float* re_w3 = (const float*)d_in[13];
  const float* re_b3 = (const float*)d_in[14];
  const float* qkv_w = (const float*)d_in[15];
  const float* qkv_b = (const float*)d_in[16];
  const float* rconv_w = (const float*)d_in[17];
  const float* rconv_b = (const float*)d_in[18];
  const float* proj_w = (const float*)d_in[19];
  const float* proj_b = (const float*)d_in[20];
  const float* ln1_g = (const float*)d_in[21];
  const float* ln1_b = (const float*)d_in[22];
  const float* ln2_g = (const float*)d_in[23];
  const float* ln2_b = (const float*)d_in[24];
  const float* ln3_g = (const float*)d_in[25];
  const float* ln3_b = (const float*)d_in[26];
  const float* mw1 = (const float*)d_in[27];
  const float* mb1 = (const float*)d_in[28];
  const float* mw2 = (const float*)d_in[29];
  const float* mb2 = (const float*)d_in[30];
  const float* ng = (const float*)d_in[31];
  const float* nb = (const float*)d_in[32];
  const float* dw1 = (const float*)d_in[33];
  const float* db1 = (const float*)d_in[34];
  const float* dw2 = (const float*)d_in[35];
  const float* db2 = (const float*)d_in[36];
  const float* dw3 = (const float*)d_in[37];
  const float* db3 = (const float*)d_in[38];

  char* ws = (char*)d_ws;
  size_t off = 0;
  auto alloc = [&](size_t bytes) -> void* {
    void* p = ws + off;
    off += (bytes + 255) & ~(size_t)255;
    return p;
  };
  bf16* attnR = (bf16*)alloc((size_t)DEPTHd * Bb * Hh * Nn * Nn * 2);
  bf16* Wt1 = (bf16*)alloc(256 * 32 * 2);
  bf16* Wt2 = (bf16*)alloc(256 * 256 * 2);
  bf16* Wt3 = (bf16*)alloc(128 * 256 * 2);
  bf16* gWt = (bf16*)alloc(32 * 128 * 2);
  float* sgW = (float*)alloc(32 * 4);
  float* bconst = (float*)alloc(32 * 4);
  bf16* Wj1 = (bf16*)alloc(256 * 96 * 2);
  bf16* Wj2 = (bf16*)alloc(256 * 256 * 2);
  bf16* Wj3 = (bf16*)alloc(128 * 256 * 2);
  bf16* Wq = (bf16*)alloc(4 * 384 * 128 * 2);
  bf16* Wp = (bf16*)alloc(4 * 128 * 128 * 2);
  bf16* Wm1 = (bf16*)alloc(4 * 128 * 128 * 2);
  bf16* Wm2 = (bf16*)alloc(4 * 128 * 128 * 2);
  bf16* Wd1 = (bf16*)alloc(256 * 128 * 2);
  bf16* Wd2 = (bf16*)alloc(512 * 256 * 2);
  bf16* Wd3 = (bf16*)alloc(128 * 512 * 2);
  float* jf = (float*)alloc((size_t)BN * 128 * 4);
  bf16* obuf = (bf16*)alloc((size_t)BN * 128 * 2);
  char* U = (char*)alloc((size_t)BN * 384 * 4);
  float* qkvb = (float*)U;
  bf16* u1 = (bf16*)U;
  bf16* u2 = (bf16*)(U + (size_t)BN * 256 * 2);

  k_prep<<<dim3(768), dim3(256), 0, stream>>>(
      re_w1, re_w2, re_w3, ln2_g, ln2_b, rconv_w, rconv_b, je_w1, je_w2, je_w3,
      qkv_w, proj_w, mw1, mw2, dw1, dw2, dw3, Wt1, Wt2, Wt3, gWt, sgW, bconst,
      Wj1, Wj2, Wj3, Wq, Wp, Wm1, Wm2, Wd1, Wd2, Wd3);

  // relation encoder (fills all of attnR)
  k_relfused<<<dim3(RTOT / 64), dim3(256), 0, stream>>>(
      relation_in, Wt1, re_b1, Wt2, re_b2, Wt3, re_b3, gWt, sgW, bconst, attnR);

  // joint encoder: 96 -> 256 -> 256 -> 128
  k_gemm_mfma<float, bf16, false, false><<<dim3(2, 16), dim3(256), 0, stream>>>(
      joint_in, 96, 96, Wj1, je_b1, u1, 256, 256, nullptr);
  k_gemm_mfma<bf16, bf16, false, false><<<dim3(2, 16), dim3(256), 0, stream>>>(
      u1, 256, 256, Wj2, je_b2, u2, 256, 256, nullptr);
  k_gemm_mfma<bf16, float, false, false><<<dim3(1, 16), dim3(256), 0, stream>>>(
      u2, 256, 256, Wj3, je_b3, jf, 128, 128, nullptr);

  // transformer blocks: 3 dispatches per depth
  for (int d = 0; d < DEPTHd; ++d) {
    k_lnqkv<float><<<dim3(3, 16), dim3(256), 0, stream>>>(
        jf, ln1_g + d * 128, ln1_b + d * 128, Wq + (size_t)d * 49152, qkv_b + d * 384,
        qkvb, 384, 384);
    k_attn<<<dim3(Nn, Hh, Bb), dim3(256), 0, stream>>>(
        qkvb, attnR + (size_t)d * Bb * Hh * Nn * Nn, conn, obuf);
    k_tail<<<dim3(16), dim3(256), 0, stream>>>(
        obuf, jf, Wp + (size_t)d * 16384, proj_b + d * 128, ln3_g + d * 128,
        ln3_b + d * 128, Wm1 + (size_t)d * 16384, mb1 + d * 128,
        Wm2 + (size_t)d * 16384, mb2 + d * 128);
  }

  // final LN fused into decoder layer 1; then 256 -> 512 -> 90
  k_lnqkv<bf16><<<dim3(2, 16), dim3(256), 0, stream>>>(jf, ng, nb, Wd1, db1, u1, 256,
                                                       256);
  k_gemm_mfma<bf16, bf16, false, false><<<dim3(4, 16), dim3(256), 0, stream>>>(
      u1, 256, 256, Wd2, db2, u2, 512, 512, nullptr);
  k_gemm_mfma<bf16, float, false, false><<<dim3(1, 16), dim3(256), 0, stream>>>(
      u2, 512, 512, Wd3, db3, (float*)d_out, 90, 90, nullptr);
}